// Round 9
// baseline (833.933 us; speedup 1.0000x reference)
//
#include <hip/hip_runtime.h>

#define N_NODES  50000
#define N_EDGES  400000
#define DIM      128
#define N_MOVIE  20400
#define N_GENRE  30
#define L_MAX    680
#define NROWS    (N_GENRE * L_MAX)   /* 20400 */
#define FF       2048
#define N_LAYERS 4

// bucketed CSR build
#define NBKT 98          /* bucket = dst >> 9 (512 nodes per bucket) */
#define NPB  512
#define ECAP 4608        /* edges per bucket capacity (mean 4096 + 8 sigma) */
#define SCAP 5120        /* CSR per bucket capacity (edges + selfs) */
#define EPGB (NBKT * ECAP)
#define SPGB (NBKT * SCAP)

typedef __attribute__((ext_vector_type(8))) short bf16x8;
typedef __attribute__((ext_vector_type(4))) float f32x4;

#define MFMA16 __builtin_amdgcn_mfma_f32_16x16x32_bf16

__device__ __forceinline__ float b2f(ushort u) {
    union { unsigned i; float f; } c; c.i = ((unsigned)u) << 16; return c.f;
}
__device__ __forceinline__ ushort f2b(float f) {
    union { float f; unsigned i; } c; c.f = f;
    unsigned u = c.i;
    u += 0x7FFFu + ((u >> 16) & 1u);   // RNE
    return (ushort)(u >> 16);
}
__device__ __forceinline__ bf16x8 load8s(const ushort* p) {
    return *(const bf16x8*)p;
}
__device__ __forceinline__ void async16(const ushort* g, ushort* l) {
    __builtin_amdgcn_global_load_lds(
        (const __attribute__((address_space(1))) void*)g,
        (__attribute__((address_space(3))) void*)l, 16, 0, 0);
}

__device__ __forceinline__ void cvt8(const float* s, ushort* d, int i) {
    const float4* q = (const float4*)(s + (size_t)i * 8);
    float4 a = q[0], b = q[1];
    bf16x8 r;
    r[0] = (short)f2b(a.x); r[1] = (short)f2b(a.y);
    r[2] = (short)f2b(a.z); r[3] = (short)f2b(a.w);
    r[4] = (short)f2b(b.x); r[5] = (short)f2b(b.y);
    r[6] = (short)f2b(b.z); r[7] = (short)f2b(b.w);
    *(bf16x8*)(d + (size_t)i * 8) = r;
}

// fp32 -> bf16, 8 elems/thread
__global__ void cvt32(const float* __restrict__ s, ushort* __restrict__ d, int n8)
{
    int i = blockIdx.x * blockDim.x + threadIdx.x;
    if (i < n8) cvt8(s, d, i);
}

// all 7 weight tensors in one launch (blockIdx.y selects tensor)
__global__ void cvt_w(const float* gatW, const float* decW, const float* qkvW,
                      const float* outW, const float* fw1, const float* fw2,
                      const float* fusW,
                      ushort* gatWb, ushort* decWb, ushort* qkvWb,
                      ushort* outWb, ushort* fw1b, ushort* fw2b, ushort* fusWb)
{
    const float* s; ushort* d; int n8;
    switch (blockIdx.y) {
        case 0: s = gatW; d = gatWb; n8 = 49152 / 8; break;
        case 1: s = decW; d = decWb; n8 = 49152 / 8; break;
        case 2: s = qkvW; d = qkvWb; n8 = 196608 / 8; break;
        case 3: s = outW; d = outWb; n8 = 65536 / 8; break;
        case 4: s = fw1;  d = fw1b;  n8 = 1048576 / 8; break;
        case 5: s = fw2;  d = fw2b;  n8 = 1048576 / 8; break;
        default: s = fusW; d = fusWb; n8 = 32768 / 8; break;
    }
    int i = blockIdx.x * 256 + threadIdx.x;
    if (i < n8) cvt8(s, d, i);
}

// ============ LDS-staged GEMM v2: full K=128 panel per stage ============
// C[M,N] = epi(A @ W^T + bias). K multiple of 128. XOR segment swizzle both-sides.
// blockIdx.z = slice index: W += z*wstride, OBF1 out += z*cstride.
// OBF: 0 = f32 out, 1 = bf16 out (LDS-staged coalesced write, BM=128 only).
template<int BM, int ACT, int EPI, int OBF>
__global__ __launch_bounds__(256) void gemm_lds(
    const ushort* __restrict__ A, const ushort* __restrict__ W_,
    const float* __restrict__ bias, void* __restrict__ Cv,
    int M, int N, int K, float scale, size_t wstride, size_t cstride)
{
    __shared__ ushort smem[BM * 128 + 128 * 128];
    ushort* As = smem;
    ushort* Ws = smem + BM * 128;
    const int tid  = threadIdx.x;
    const int wave = tid >> 6, lane = tid & 63;
    const int quad = lane >> 4, l16 = lane & 15;
    const int m0 = blockIdx.x * BM;
    const int n0 = blockIdx.y * 128;
    const int hop = blockIdx.z;
    const ushort* W = W_ + (size_t)hop * wstride;

    constexpr int MT = BM / 32;
    const int mbase = (wave & 1) * (BM / 2);
    const int nbase = (wave >> 1) * 64;

    f32x4 acc[MT][4] = {};
    for (int k0 = 0; k0 < K; k0 += 128) {
        if (k0) __syncthreads();
#pragma unroll
        for (int i = 0; i < BM / 16; i++) {
            int seg = i * 256 + tid;
            int r = seg >> 4, s = seg & 15;
            int rg = min(m0 + r, M - 1);
            async16(A + (size_t)rg * K + k0 + ((s ^ (r & 15)) * 8),
                    As + r * 128 + s * 8);
        }
#pragma unroll
        for (int i = 0; i < 8; i++) {
            int seg = i * 256 + tid;
            int r = seg >> 4, s = seg & 15;
            async16(W + (size_t)(n0 + r) * K + k0 + ((s ^ (r & 15)) * 8),
                    Ws + r * 128 + s * 8);
        }
        __syncthreads();

#pragma unroll
        for (int kk = 0; kk < 4; kk++) {
            bf16x8 a[MT], b[4];
#pragma unroll
            for (int mt = 0; mt < MT; mt++)
                a[mt] = load8s(As + (mbase + mt * 16 + l16) * 128 +
                               (((kk * 4 + quad) ^ l16) * 8));
#pragma unroll
            for (int nt = 0; nt < 4; nt++)
                b[nt] = load8s(Ws + (nbase + nt * 16 + l16) * 128 +
                               (((kk * 4 + quad) ^ l16) * 8));
#pragma unroll
            for (int mt = 0; mt < MT; mt++)
#pragma unroll
                for (int nt = 0; nt < 4; nt++)
                    acc[mt][nt] = MFMA16(a[mt], b[nt], acc[mt][nt], 0, 0, 0);
        }
    }

    if constexpr (OBF == 1) {
        static_assert(BM == 128, "OBF=1 staged epilogue assumes BM=128");
        ushort* Cs = smem;
        __syncthreads();
#pragma unroll
        for (int p = 0; p < 2; p++) {
            if ((wave & 1) == p) {
#pragma unroll
                for (int nt = 0; nt < 4; nt++) {
                    const int col = nbase + nt * 16 + l16;
                    const float bv = bias ? bias[n0 + col] : 0.f;
#pragma unroll
                    for (int mt = 0; mt < MT; mt++) {
                        const int rl = mt * 16 + quad * 4;
#pragma unroll
                        for (int r = 0; r < 4; r++) {
                            float v = acc[mt][nt][r] + bv;
                            if (ACT == 1) v = (v >= 0.f) ? v : 0.01f * v;
                            if (ACT == 2) v = fmaxf(v, 0.f);
                            Cs[(rl + r) * 128 + col] = f2b(v);
                        }
                    }
                }
            }
            __syncthreads();
            const int row = tid >> 2, cb = (tid & 3) * 32;   // 32 shorts = 64B
            const int grow = m0 + p * 64 + row;
            if (grow < M) {
                const ushort* s = Cs + row * 128 + cb;
                ushort* dp = (ushort*)Cv + (size_t)hop * cstride +
                             (size_t)grow * N + n0 + cb;
                *(int4*)(dp)      = *(const int4*)(s);
                *(int4*)(dp + 8)  = *(const int4*)(s + 8);
                *(int4*)(dp + 16) = *(const int4*)(s + 16);
                *(int4*)(dp + 24) = *(const int4*)(s + 24);
            }
            __syncthreads();
        }
    } else {
#pragma unroll
        for (int nt = 0; nt < 4; nt++) {
            const int col = n0 + nbase + nt * 16 + l16;
            const float bv = bias ? bias[col] : 0.f;
#pragma unroll
            for (int mt = 0; mt < MT; mt++) {
#pragma unroll
                for (int r = 0; r < 4; r++) {
                    const int row = m0 + mbase + mt * 16 + quad * 4 + r;
                    if (row < M) {
                        float v = acc[mt][nt][r] + bv;
                        if (ACT == 1) v = (v >= 0.f) ? v : 0.01f * v;
                        if (ACT == 2) v = fmaxf(v, 0.f);
                        const size_t idx = (size_t)row * N + col;
                        if (EPI == 1) ((float*)Cv)[idx] += scale * v;
                        else          ((float*)Cv)[idx] = v;
                    }
                }
            }
        }
    }
}

// ====== merged 3-hop decoder GEMM: acc = sum_k decay_k*leaky(gbx_k@decW_k^T+b_k) ======
__global__ __launch_bounds__(256) void dec3_gemm(
    const ushort* __restrict__ gbx3, const ushort* __restrict__ decWb,
    const float* __restrict__ decB, float* __restrict__ outp, int M)
{
    __shared__ ushort smem[2 * 128 * 128];   // 64 KB
    ushort* As = smem;
    ushort* Ws = smem + 128 * 128;
    const int tid  = threadIdx.x;
    const int wave = tid >> 6, lane = tid & 63;
    const int quad = lane >> 4, l16 = lane & 15;
    const int m0 = blockIdx.x * 128;
    const int mbase = (wave & 1) * 64;
    const int nbase = (wave >> 1) * 64;
    const float decay[3] = { 1.0f, 0.90483741803595952f, 0.81873075307798182f };

    float fac[4][4][4] = {};
    for (int hop = 0; hop < 3; hop++) {
        if (hop) __syncthreads();
        const ushort* A = gbx3 + (size_t)hop * M * DIM;
        const ushort* W = decWb + hop * DIM * DIM;
#pragma unroll
        for (int i = 0; i < 8; i++) {
            int seg = i * 256 + tid;
            int r = seg >> 4, s = seg & 15;
            int rg = min(m0 + r, M - 1);
            async16(A + (size_t)rg * 128 + ((s ^ (r & 15)) * 8), As + r * 128 + s * 8);
        }
#pragma unroll
        for (int i = 0; i < 8; i++) {
            int seg = i * 256 + tid;
            int r = seg >> 4, s = seg & 15;
            async16(W + (size_t)r * 128 + ((s ^ (r & 15)) * 8), Ws + r * 128 + s * 8);
        }
        __syncthreads();
        f32x4 acc[4][4] = {};
#pragma unroll
        for (int kk = 0; kk < 4; kk++) {
            bf16x8 a[4], b[4];
#pragma unroll
            for (int mt = 0; mt < 4; mt++)
                a[mt] = load8s(As + (mbase + mt * 16 + l16) * 128 +
                               (((kk * 4 + quad) ^ l16) * 8));
#pragma unroll
            for (int nt = 0; nt < 4; nt++)
                b[nt] = load8s(Ws + (nbase + nt * 16 + l16) * 128 +
                               (((kk * 4 + quad) ^ l16) * 8));
#pragma unroll
            for (int mt = 0; mt < 4; mt++)
#pragma unroll
                for (int nt = 0; nt < 4; nt++)
                    acc[mt][nt] = MFMA16(a[mt], b[nt], acc[mt][nt], 0, 0, 0);
        }
        const float dk = decay[hop];
#pragma unroll
        for (int nt = 0; nt < 4; nt++) {
            const int col = nbase + nt * 16 + l16;
            const float bv = decB[hop * DIM + col];
#pragma unroll
            for (int mt = 0; mt < 4; mt++)
#pragma unroll
                for (int r = 0; r < 4; r++) {
                    float v = acc[mt][nt][r] + bv;
                    v = (v >= 0.f) ? v : 0.01f * v;
                    fac[mt][nt][r] += dk * v;
                }
        }
    }
#pragma unroll
    for (int nt = 0; nt < 4; nt++) {
        const int col = nbase + nt * 16 + l16;
#pragma unroll
        for (int mt = 0; mt < 4; mt++)
#pragma unroll
            for (int r = 0; r < 4; r++) {
                const int row = m0 + mbase + mt * 16 + quad * 4 + r;
                if (row < M) outp[(size_t)row * 128 + col] = fac[mt][nt][r];
            }
    }
}

// ====== fused out-proj + residual + LayerNorm (post-LN attn branch) ======
__global__ __launch_bounds__(256) void proj_ln(
    const ushort* __restrict__ A, const ushort* __restrict__ W,
    const float* __restrict__ bias, float* __restrict__ y,
    const float* __restrict__ g, const float* __restrict__ b,
    ushort* __restrict__ yb, int M)
{
    __shared__ ushort smem[64 * 128 + 128 * 128];   // 48 KB
    __shared__ float lnsum[64][2], lnsq[64][2];
    ushort* As = smem;
    ushort* Ws = smem + 64 * 128;
    const int tid  = threadIdx.x;
    const int wave = tid >> 6, lane = tid & 63;
    const int quad = lane >> 4, l16 = lane & 15;
    const int m0 = blockIdx.x * 64;
    const int mbase = (wave & 1) * 32;
    const int nbase = (wave >> 1) * 64;
    const int half = wave >> 1;

#pragma unroll
    for (int i = 0; i < 4; i++) {
        int seg = i * 256 + tid;
        int r = seg >> 4, s = seg & 15;
        int rg = min(m0 + r, M - 1);
        async16(A + (size_t)rg * 128 + ((s ^ (r & 15)) * 8), As + r * 128 + s * 8);
    }
#pragma unroll
    for (int i = 0; i < 8; i++) {
        int seg = i * 256 + tid;
        int r = seg >> 4, s = seg & 15;
        async16(W + (size_t)r * 128 + ((s ^ (r & 15)) * 8), Ws + r * 128 + s * 8);
    }
    __syncthreads();

    f32x4 acc[2][4] = {};
#pragma unroll
    for (int kk = 0; kk < 4; kk++) {
        bf16x8 a[2], bfr[4];
#pragma unroll
        for (int mt = 0; mt < 2; mt++)
            a[mt] = load8s(As + (mbase + mt * 16 + l16) * 128 +
                           (((kk * 4 + quad) ^ l16) * 8));
#pragma unroll
        for (int nt = 0; nt < 4; nt++)
            bfr[nt] = load8s(Ws + (nbase + nt * 16 + l16) * 128 +
                             (((kk * 4 + quad) ^ l16) * 8));
#pragma unroll
        for (int mt = 0; mt < 2; mt++)
#pragma unroll
            for (int nt = 0; nt < 4; nt++)
                acc[mt][nt] = MFMA16(a[mt], bfr[nt], acc[mt][nt], 0, 0, 0);
    }

    // residual add + row partial sums
    float vv[2][4][4];
    float rs[2][4] = {};
#pragma unroll
    for (int mt = 0; mt < 2; mt++)
#pragma unroll
        for (int nt = 0; nt < 4; nt++) {
            const int col = nbase + nt * 16 + l16;
            const float bv = bias[col];
#pragma unroll
            for (int rr = 0; rr < 4; rr++) {
                const int row = m0 + mbase + mt * 16 + quad * 4 + rr;
                float v = acc[mt][nt][rr] + bv;
                if (row < M) v += y[(size_t)row * 128 + col];
                vv[mt][nt][rr] = v;
                rs[mt][rr] += v;
            }
        }
#pragma unroll
    for (int mt = 0; mt < 2; mt++)
#pragma unroll
        for (int rr = 0; rr < 4; rr++) {
#pragma unroll
            for (int off = 1; off <= 8; off <<= 1)
                rs[mt][rr] += __shfl_xor(rs[mt][rr], off, 64);
            if (l16 == 0)
                lnsum[mbase + mt * 16 + quad * 4 + rr][half] = rs[mt][rr];
        }
    __syncthreads();

    float mean[2][4];
#pragma unroll
    for (int mt = 0; mt < 2; mt++)
#pragma unroll
        for (int rr = 0; rr < 4; rr++) {
            const int rl = mbase + mt * 16 + quad * 4 + rr;
            mean[mt][rr] = (lnsum[rl][0] + lnsum[rl][1]) * (1.f / 128.f);
            float q = 0.f;
#pragma unroll
            for (int nt = 0; nt < 4; nt++) {
                float d = vv[mt][nt][rr] - mean[mt][rr];
                q += d * d;
            }
#pragma unroll
            for (int off = 1; off <= 8; off <<= 1)
                q += __shfl_xor(q, off, 64);
            if (l16 == 0) lnsq[rl][half] = q;
        }
    __syncthreads();

#pragma unroll
    for (int mt = 0; mt < 2; mt++)
#pragma unroll
        for (int rr = 0; rr < 4; rr++) {
            const int rl = mbase + mt * 16 + quad * 4 + rr;
            const int row = m0 + rl;
            const float rstd = rsqrtf((lnsq[rl][0] + lnsq[rl][1]) * (1.f / 128.f) + 1e-5f);
            if (row < M) {
#pragma unroll
                for (int nt = 0; nt < 4; nt++) {
                    const int col = nbase + nt * 16 + l16;
                    float o = (vv[mt][nt][rr] - mean[mt][rr]) * rstd * g[col] + b[col];
                    y[(size_t)row * 128 + col] = o;
                    yb[(size_t)row * 128 + col] = f2b(o);
                }
            }
        }
}

// ====== merged QKV + V^T GEMM: grid (160, 3) ======
__global__ __launch_bounds__(256) void qkv_gemm(
    const ushort* __restrict__ A, const ushort* __restrict__ W0,
    const float* __restrict__ bias0, ushort* __restrict__ qkv,
    ushort* __restrict__ vt, int M)
{
    __shared__ ushort smem[2 * 128 * 128];
    ushort* As = smem;
    ushort* Ws = smem + 128 * 128;
    const int tid  = threadIdx.x;
    const int wave = tid >> 6, lane = tid & 63;
    const int quad = lane >> 4, l16 = lane & 15;
    const int m0 = blockIdx.x * 128;
    const int sel = blockIdx.y;
    const ushort* W = W0 + (size_t)sel * 128 * 128;
    const int mbase = (wave & 1) * 64;
    const int nbase = (wave >> 1) * 64;

    f32x4 acc[4][4] = {};
#pragma unroll
    for (int i = 0; i < 8; i++) {
        int seg = i * 256 + tid;
        int r = seg >> 4, s = seg & 15;
        int rg = min(m0 + r, M - 1);
        async16(A + (size_t)rg * 128 + ((s ^ (r & 15)) * 8), As + r * 128 + s * 8);
    }
#pragma unroll
    for (int i = 0; i < 8; i++) {
        int seg = i * 256 + tid;
        int r = seg >> 4, s = seg & 15;
        async16(W + (size_t)r * 128 + ((s ^ (r & 15)) * 8), Ws + r * 128 + s * 8);
    }
    __syncthreads();
#pragma unroll
    for (int kk = 0; kk < 4; kk++) {
        bf16x8 a[4], b[4];
#pragma unroll
        for (int mt = 0; mt < 4; mt++)
            a[mt] = load8s(As + (mbase + mt * 16 + l16) * 128 +
                           (((kk * 4 + quad) ^ l16) * 8));
#pragma unroll
        for (int nt = 0; nt < 4; nt++)
            b[nt] = load8s(Ws + (nbase + nt * 16 + l16) * 128 +
                           (((kk * 4 + quad) ^ l16) * 8));
#pragma unroll
        for (int mt = 0; mt < 4; mt++)
#pragma unroll
            for (int nt = 0; nt < 4; nt++)
                acc[mt][nt] = MFMA16(a[mt], b[nt], acc[mt][nt], 0, 0, 0);
    }

    if (sel < 2) {
        ushort* Cs = smem;
        __syncthreads();
#pragma unroll
        for (int p = 0; p < 2; p++) {
            if ((wave & 1) == p) {
#pragma unroll
                for (int nt = 0; nt < 4; nt++) {
                    const int col = nbase + nt * 16 + l16;
                    const float bv = bias0[sel * 128 + col];
#pragma unroll
                    for (int mt = 0; mt < 4; mt++) {
                        const int rl = mt * 16 + quad * 4;
#pragma unroll
                        for (int r = 0; r < 4; r++)
                            Cs[(rl + r) * 128 + col] = f2b(acc[mt][nt][r] + bv);
                    }
                }
            }
            __syncthreads();
            const int row = tid >> 2, cb = (tid & 3) * 32;
            const int grow = m0 + p * 64 + row;
            if (grow < M) {
                const ushort* s = Cs + row * 128 + cb;
                ushort* dp = qkv + (size_t)grow * 256 + sel * 128 + cb;
                *(int4*)(dp)      = *(const int4*)(s);
                *(int4*)(dp + 8)  = *(const int4*)(s + 8);
                *(int4*)(dp + 16) = *(const int4*)(s + 16);
                *(int4*)(dp + 24) = *(const int4*)(s + 24);
            }
            __syncthreads();
        }
    } else {
#pragma unroll
        for (int nt = 0; nt < 4; nt++) {
            const int col = nbase + nt * 16 + l16;
            const float bv = bias0[256 + col];
#pragma unroll
            for (int mt = 0; mt < 4; mt++) {
                const int row0 = m0 + mbase + mt * 16 + quad * 4;
                if (row0 < M) {
                    ushort4 pk;
                    pk.x = f2b(acc[mt][nt][0] + bv);
                    pk.y = f2b(acc[mt][nt][1] + bv);
                    pk.z = f2b(acc[mt][nt][2] + bv);
                    pk.w = f2b(acc[mt][nt][3] + bv);
                    *(ushort4*)(vt + (size_t)col * M + row0) = pk;
                }
            }
        }
    }
}

// ====== Fused FFN (R4-proven): LDS-staged weights, 4 FF-quarters ======
// launch_bounds min-waves=3 -> regalloc/runtime provision 3 blocks/CU (12 waves):
// grid 640 fits in 768 slots -> whole dispatch co-resident, no tail rounds.
__global__ __launch_bounds__(256, 3) void ffn_fused(
    const ushort* __restrict__ y, const ushort* __restrict__ w1,
    const float* __restrict__ b1, const ushort* __restrict__ w2,
    const float* __restrict__ b2,
    float* __restrict__ o0, float* __restrict__ o1,
    float* __restrict__ o2, float* __restrict__ o3, int M)
{
    __shared__ ushort f1s[2][32 * 128];   // 2x8 KB
    __shared__ ushort f2s[2][128 * 32];   // 2x8 KB
    __shared__ ushort mids[4][32 * 40];   // 10 KB wave-private
    const int tid  = threadIdx.x;
    const int wave = tid >> 6, lane = tid & 63;
    const int quad = lane >> 4, l16 = lane & 15;
    const int m0 = blockIdx.x * 128;
    const int fh = blockIdx.y;
    const int fbase = fh * (FF / 4);
    float* o = (fh == 0) ? o0 : (fh == 1) ? o1 : (fh == 2) ? o2 : o3;

    const int sw1 = ((tid & 15) ^ (tid >> 4)) * 8;
    const int sw2 = ((tid & 3) ^ ((tid >> 3) & 3)) * 8;

    const int wrow = m0 + wave * 32;
    bf16x8 yf[2][4];
#pragma unroll
    for (int mt = 0; mt < 2; mt++) {
        const int mr = min(wrow + mt * 16 + l16, M - 1);
#pragma unroll
        for (int ks = 0; ks < 4; ks++)
            yf[mt][ks] = load8s(y + (size_t)mr * 128 + ks * 32 + quad * 8);
    }

#pragma unroll
    for (int i = 0; i < 2; i++) {
        int row = i * 16 + (tid >> 4);
        async16(w1 + (size_t)(fbase + row) * 128 + sw1,
                f1s[0] + row * 128 + (tid & 15) * 8);
    }
#pragma unroll
    for (int i = 0; i < 2; i++) {
        int row = i * 64 + (tid >> 2);
        async16(w2 + (size_t)row * FF + fbase + sw2,
                f2s[0] + row * 32 + (tid & 3) * 8);
    }

    f32x4 oacc[2][8] = {};
    ushort* midw = mids[wave];
    int cur = 0;
    __syncthreads();

    for (int fo = 0; fo < FF / 4; fo += 32) {
        if (fo + 32 < FF / 4) {
            const int fn = fbase + fo + 32;
#pragma unroll
            for (int i = 0; i < 2; i++) {
                int row = i * 16 + (tid >> 4);
                async16(w1 + (size_t)(fn + row) * 128 + sw1,
                        f1s[cur ^ 1] + row * 128 + (tid & 15) * 8);
            }
#pragma unroll
            for (int i = 0; i < 2; i++) {
                int row = i * 64 + (tid >> 2);
                async16(w2 + (size_t)row * FF + fn + sw2,
                        f2s[cur ^ 1] + row * 32 + (tid & 3) * 8);
            }
        }
        const ushort* F1 = f1s[cur];
        const ushort* F2 = f2s[cur];

        f32x4 midacc[2][2] = {};
#pragma unroll
        for (int ks = 0; ks < 4; ks++) {
            const int csA = (((ks * 4 + quad) ^ l16) & 15) * 8;
#pragma unroll
            for (int ft = 0; ft < 2; ft++) {
                bf16x8 wf = load8s(F1 + (ft * 16 + l16) * 128 + csA);
                midacc[0][ft] = MFMA16(wf, yf[0][ks], midacc[0][ft], 0, 0, 0);
                midacc[1][ft] = MFMA16(wf, yf[1][ks], midacc[1][ft], 0, 0, 0);
            }
        }
#pragma unroll
        for (int mt = 0; mt < 2; mt++)
#pragma unroll
            for (int ft = 0; ft < 2; ft++) {
                const float4 bb = *(const float4*)(b1 + fbase + fo + ft * 16 + quad * 4);
                ushort4 pk;
                pk.x = f2b(fmaxf(midacc[mt][ft][0] + bb.x, 0.f));
                pk.y = f2b(fmaxf(midacc[mt][ft][1] + bb.y, 0.f));
                pk.z = f2b(fmaxf(midacc[mt][ft][2] + bb.z, 0.f));
                pk.w = f2b(fmaxf(midacc[mt][ft][3] + bb.w, 0.f));
                *(ushort4*)(midw + (mt * 16 + l16) * 40 + ft * 16 + quad * 4) = pk;
            }
        bf16x8 mf0 = load8s(midw + (size_t)l16 * 40 + quad * 8);
        bf16x8 mf1 = load8s(midw + (size_t)(16 + l16) * 40 + quad * 8);
        const int gB = (quad ^ ((l16 >> 1) & 3)) * 8;
#pragma unroll
        for (int dt = 0; dt < 8; dt++) {
            bf16x8 wf = load8s(F2 + (dt * 16 + l16) * 32 + gB);
            oacc[0][dt] = MFMA16(wf, mf0, oacc[0][dt], 0, 0, 0);
            oacc[1][dt] = MFMA16(wf, mf1, oacc[1][dt], 0, 0, 0);
        }
        __syncthreads();
        cur ^= 1;
    }

#pragma unroll
    for (int mt = 0; mt < 2; mt++) {
        const int m = wrow + mt * 16 + l16;
        if (m < M) {
            float* op = o + (size_t)m * 128 + quad * 4;
#pragma unroll
            for (int dt = 0; dt < 8; dt++) {
                float4 v;
                if (fh == 0) {
                    const float4 bv = *(const float4*)(b2 + dt * 16 + quad * 4);
                    v.x = oacc[mt][dt][0] + bv.x;
                    v.y = oacc[mt][dt][1] + bv.y;
                    v.z = oacc[mt][dt][2] + bv.z;
                    v.w = oacc[mt][dt][3] + bv.w;
                } else {
                    v.x = oacc[mt][dt][0];
                    v.y = oacc[mt][dt][1];
                    v.z = oacc[mt][dt][2];
                    v.w = oacc[mt][dt][3];
                }
                *(float4*)(op + dt * 16) = v;
            }
        }
    }
}

// per-(node,head) attention logits, all 3 hops in one launch (blockIdx.y = hop)
__global__ void gat_al(const ushort* __restrict__ hb3,
                       const float* __restrict__ asrc, const float* __restrict__ adst,
                       float* __restrict__ als3, float* __restrict__ ald3, int N)
{
    int idx = blockIdx.x * blockDim.x + threadIdx.x;
    if (idx >= N * 4) return;
    const int hop = blockIdx.y;
    const ushort* h = hb3 + (size_t)hop * N * DIM;
    const float* as_ = asrc + hop * DIM;
    const float* ad_ = adst + hop * DIM;
    int n = idx >> 2, hh = idx & 3;
    const ushort* hp = h + (size_t)n * DIM + hh * 32;
    float s = 0.f, d = 0.f;
#pragma unroll
    for (int q = 0; q < 4; q++) {
        bf16x8 hv = load8s(hp + q * 8);
#pragma unroll
        for (int c = 0; c < 8; c++) {
            float v = b2f((ushort)hv[c]);
            s += v * as_[hh * 32 + q * 8 + c];
            d += v * ad_[hh * 32 + q * 8 + c];
        }
    }
    als3[(size_t)hop * N * 4 + idx] = s;
    ald3[(size_t)hop * N * 4 + idx] = d;
}

// ---------------- bucketed CSR build ----------------
__global__ void csr_initb(int* __restrict__ bcur)
{
    int i = blockIdx.x * 256 + threadIdx.x;
    if (i < 3 * NBKT) bcur[i * 16] = (i % NBKT) * ECAP;
}

__global__ __launch_bounds__(256) void csr_route(
    const int* __restrict__ e0, const int* __restrict__ e1, const int* __restrict__ e2,
    int* __restrict__ bcur, int* __restrict__ ebuf)
{
    __shared__ int hist[NBKT], base[NBKT], cur[NBKT];
    const int g = blockIdx.y, t = threadIdx.x;
    const int* e = (g == 0) ? e0 : (g == 1) ? e1 : e2;
    const int i0 = blockIdx.x * 4096;
    for (int j = t; j < NBKT; j += 256) { hist[j] = 0; cur[j] = 0; }
    __syncthreads();
    unsigned pk[16]; int bk[16];
#pragma unroll
    for (int j = 0; j < 16; j++) {
        int i = i0 + j * 256 + t;
        if (i < N_EDGES) {
            int s = e[i], d = e[N_EDGES + i];
            bk[j] = d >> 9;
            pk[j] = (unsigned)s | ((unsigned)(d & 511) << 16);
            atomicAdd(&hist[bk[j]], 1);
        } else bk[j] = -1;
    }
    __syncthreads();
    for (int j = t; j < NBKT; j += 256)
        if (hist[j]) base[j] = atomicAdd(&bcur[(g * NBKT + j) * 16], hist[j]);
    __syncthreads();
#pragma unroll
    for (int j = 0; j < 16; j++)
        if (bk[j] >= 0) {
            int p = base[bk[j]] + atomicAdd(&cur[bk[j]], 1);
            ebuf[(size_t)g * EPGB + p] = (int)pk[j];
        }
}

__global__ __launch_bounds__(256) void csr_build(
    const int* __restrict__ bcur, const int* __restrict__ ebuf,
    int* __restrict__ off, int* __restrict__ deg, int* __restrict__ srcs)
{
    __shared__ int hist[NPB];
    __shared__ int part[256];
    const int g = blockIdx.y, b = blockIdx.x, t = threadIdx.x;
    const int nb0 = b * NPB;
    const int nn = min(NPB, N_NODES - nb0);
    const int cnt = bcur[(g * NBKT + b) * 16] - b * ECAP;
    const int* eb = ebuf + (size_t)g * EPGB + b * ECAP;

    for (int j = t; j < NPB; j += 256) hist[j] = (j < nn) ? 1 : 0;   // self-loop
    __syncthreads();
    for (int i = t; i < cnt; i += 256)
        atomicAdd(&hist[(eb[i] >> 16) & 511], 1);
    __syncthreads();

    int a0 = hist[t * 2], a1 = hist[t * 2 + 1];
    int sum = a0 + a1;
    part[t] = sum;
    __syncthreads();
    for (int d = 1; d < 256; d <<= 1) {
        int x = (t >= d) ? part[t - d] : 0;
        __syncthreads();
        part[t] += x;
        __syncthreads();
    }
    const int excl = part[t] - sum;
    __syncthreads();
    const int sb = b * SCAP;
    hist[t * 2]     = excl;
    hist[t * 2 + 1] = excl + a0;
    if (t * 2 < nn) {
        off[(size_t)g * N_NODES + nb0 + t * 2] = sb + excl;
        deg[(size_t)g * N_NODES + nb0 + t * 2] = a0;
    }
    if (t * 2 + 1 < nn) {
        off[(size_t)g * N_NODES + nb0 + t * 2 + 1] = sb + excl + a0;
        deg[(size_t)g * N_NODES + nb0 + t * 2 + 1] = a1;
    }
    __syncthreads();

    int* sg = srcs + (size_t)g * SPGB + sb;
    for (int i = t; i < cnt; i += 256) {
        int v = eb[i];
        int p = atomicAdd(&hist[(v >> 16) & 511], 1);
        sg[p] = v & 0xFFFF;
    }
    for (int j = t; j < nn; j += 256) {
        int p = atomicAdd(&hist[j], 1);
        sg[p] = nb0 + j;
    }
}

// one wave per dst, 4 edge-groups x 16 lanes; all 3 hops (blockIdx.y = hop)
__global__ __launch_bounds__(256) void gat_gather(
    const int* __restrict__ off3, const int* __restrict__ deg3,
    const int* __restrict__ srcs3, const ushort* __restrict__ hb3,
    const float* __restrict__ als3, const float* __restrict__ ald3,
    const float* __restrict__ bias3, ushort* __restrict__ gbx3)
{
    int w = (blockIdx.x * 256 + threadIdx.x) >> 6;
    int lane = threadIdx.x & 63;
    if (w >= N_NODES) return;
    const int hop = blockIdx.y;
    const int* off = off3 + (size_t)hop * N_NODES;
    const int* deg = deg3 + (size_t)hop * N_NODES;
    const int* srcs = srcs3 + (size_t)hop * SPGB;
    const ushort* hb = hb3 + (size_t)hop * N_NODES * DIM;
    const float* als = als3 + (size_t)hop * N_NODES * 4;
    const float* ald = ald3 + (size_t)hop * N_NODES * 4;
    const float* bias = bias3 + hop * DIM;
    ushort* ob = gbx3 + (size_t)hop * N_NODES * DIM;

    const int grp  = lane >> 4;
    const int l16  = lane & 15;
    const int head = l16 >> 2;
    const float adv = ald[(size_t)w * 4 + head];
    const int jb = off[w], dg = deg[w];

    float acc[8] = {};
    float wsum = 0.f;

    int j = grp;
    int s = (j < dg) ? srcs[jb + j] : 0;
    while (j < dg) {
        const int jn = j + 4;
        const int sn = (jn < dg) ? srcs[jb + jn] : 0;
        bf16x8 hv = load8s(hb + (size_t)s * DIM + l16 * 8);
        float e = als[(size_t)s * 4 + head] + adv;
        e = (e >= 0.f) ? e : 0.2f * e;
        const float wg = __expf(e);
        wsum += wg;
#pragma unroll
        for (int c = 0; c < 8; c++) acc[c] += wg * b2f((ushort)hv[c]);
        j = jn; s = sn;
    }

    wsum += __shfl_xor(wsum, 16, 64);
    wsum += __shfl_xor(wsum, 32, 64);
#pragma unroll
    for (int c = 0; c < 8; c++) {
        acc[c] += __shfl_xor(acc[c], 16, 64);
        acc[c] += __shfl_xor(acc[c], 32, 64);
    }

    if (grp == 0) {
        const float inv = 1.f / wsum;
        bf16x8 r;
#pragma unroll
        for (int c = 0; c < 8; c++)
            r[c] = (short)f2b(acc[c] * inv + bias[l16 * 8 + c]);
        *(bf16x8*)(ob + (size_t)w * DIM + l16 * 8) = r;
    }
}

__global__ void calc_pos(const int* __restrict__ genre, int* __restrict__ pos,
                         int* __restrict__ cnt, int NM)
{
    int i = blockIdx.x * blockDim.x + threadIdx.x;
    if (i < NM) pos[i] = atomicAdd(&cnt[genre[i]], 1);
}

__global__ void build_y(const float* __restrict__ acc, const int* __restrict__ midx,
                        const int* __restrict__ genre, const int* __restrict__ pos,
                        float* __restrict__ y, ushort* __restrict__ yb)
{
    int i = blockIdx.x, c = threadIdx.x;
    int g = genre[i], p = pos[i];
    float v = acc[(size_t)midx[i] * DIM + c];
    size_t o = ((size_t)g * L_MAX + p) * DIM + c;
    y[o] = v; yb[o] = f2b(v);
}

// ======== barrier-free flash attention: V^T pre-transposed in global ========
#define SP 40    /* P row stride in shorts (80 B, 16B-aligned) */

__global__ __launch_bounds__(256) void flash_attn(
    const ushort* __restrict__ qk, const ushort* __restrict__ vtg,
    const int* __restrict__ cnt, ushort* __restrict__ o)
{
    __shared__ ushort Pb[4][32 * SP];     // 10240 B, wave-private tiles

    const int qt = blockIdx.x, hh = blockIdx.y, g = blockIdx.z;
    const int t = threadIdx.x, wave = t >> 6, lane = t & 63;
    const int quad = lane >> 4, l16 = lane & 15;
    const int L = cnt[g];
    const float scale = 0.17677669529663687f;   // 1/sqrt(32)
    const ushort* base = qk + (size_t)g * L_MAX * 256;
    const ushort* vb0 = vtg + (size_t)(hh * 32 + l16) * NROWS + g * L_MAX;
    const ushort* vb1 = vb0 + (size_t)16 * NROWS;

    const int q0 = qt * 128 + wave * 32;
    bf16x8 a0 = load8s(base + (size_t)min(q0 + l16,      L_MAX - 1) * 256 + hh * 32 + quad * 8);
    bf16x8 a1 = load8s(base + (size_t)min(q0 + 16 + l16, L_MAX - 1) * 256 + hh * 32 + quad * 8);

    f32x4 oacc[2][2] = {};        // [dhalf][qhalf], O^T layout
    float rsum[2] = {0.f, 0.f};
    ushort* P = Pb[wave];

    for (int kt = 0; kt < 704; kt += 32) {
        bf16x8 b0 = load8s(base + (size_t)min(kt + l16,      L_MAX - 1) * 256 + 128 + hh * 32 + quad * 8);
        bf16x8 b1 = load8s(base + (size_t)min(kt + 16 + l16, L_MAX - 1) * 256 + 128 + hh * 32 + quad * 8);
        f32x4 z = {};
        __builtin_amdgcn_s_setprio(1);
        f32x4 st00 = MFMA16(b0, a0, z, 0, 0, 0);   // S^T[k][q]
        f32x4 st01 = MFMA16(b0, a1, z, 0, 0, 0);
        f32x4 st10 = MFMA16(b1, a0, z, 0, 0, 0);
        f32x4 st11 = MFMA16(b1, a1, z, 0, 0, 0);
        __builtin_amdgcn_s_setprio(0);

        const int kc0 = kt + quad * 4, kc1 = kt + 16 + quad * 4;
#pragma unroll
        for (int qh = 0; qh < 2; qh++) {
            const f32x4 sA = qh ? st01 : st00;
            const f32x4 sB = qh ? st11 : st10;
            float w[8];
#pragma unroll
            for (int r = 0; r < 4; r++) {
                w[r]     = (kc0 + r < L) ? __expf(sA[r] * scale) : 0.f;
                w[4 + r] = (kc1 + r < L) ? __expf(sB[r] * scale) : 0.f;
                rsum[qh] += w[r] + w[4 + r];
            }
            ushort4 pk0, pk1;
            pk0.x = f2b(w[0]); pk0.y = f2b(w[1]); pk0.z = f2b(w[2]); pk0.w = f2b(w[3]);
            pk1.x = f2b(w[4]); pk1.y = f2b(w[5]); pk1.z = f2b(w[6]); pk1.w = f2b(w[7]);
            *(ushort4*)(P + (qh * 16 + l16) * SP + quad * 4)      = pk0;
            *(ushort4*)(P + (qh * 16 + l16) * SP + 16 + quad * 4) = pk1;
        }
        bf16x8 p0 = load8s(P + (size_t)l16 * SP + quad * 8);
        bf16x8 p1 = load8s(P + (size_t)(16 + l16) * SP + quad * 8);
        bf16x8 v0 = load8s(vb0 + kt + quad * 8);
        bf16x8 v1 = load8s(vb1 + kt + quad * 8);
        __builtin_amdgcn_s_setprio(1);
        oacc[0][0] = MFMA16(v0, p0, oacc[0][0], 0, 0, 0);
        oacc[0][1] = MFMA16(v0, p1, oacc[0][1], 0, 0, 0);
        oacc[1][0] = MFMA16(v1, p0, oacc[1][0], 0, 0, 0);
        oacc[1][1] = MFMA16(v1, p1, oacc[1][1], 0, 0, 0);
        __builtin_amdgcn_s_setprio(0);
    }

#pragma unroll
    for (int qh = 0; qh < 2; qh++) {
        float s = rsum[qh];
        s += __shfl_xor(s, 16, 64);
        s += __shfl_xor(s, 32, 64);
        const int q = q0 + qh * 16 + l16;
        if (q < L_MAX) {
            const float inv = 1.f / s;
#pragma unroll
            for (int dh = 0; dh < 2; dh++) {
                ushort4 pk;
                pk.x = f2b(oacc[dh][qh][0] * inv);
                pk.y = f2b(oacc[dh][qh][1] * inv);
                pk.z = f2b(oacc[dh][qh][2] * inv);
                pk.w = f2b(oacc[dh][qh][3] * inv);
                *(ushort4*)(o + ((size_t)(g * L_MAX + q)) * DIM + hh * 32 + dh * 16 + quad * 4) = pk;
            }
        }
    }
}

// y = LN(y + res [+ res2 [+ res3 + res4]]) * g + b; wave-per-row, no LDS/barriers.
__global__ __launch_bounds__(256) void ln_res(
    float* __restrict__ y, const float* __restrict__ res,
    const float* __restrict__ res2, const float* __restrict__ res3,
    const float* __restrict__ res4,
    const float* __restrict__ g, const float* __restrict__ b,
    ushort* __restrict__ yb)
{
    const int r = blockIdx.x * 4 + (threadIdx.x >> 6);
    const int lane = threadIdx.x & 63;
    const size_t base = (size_t)r * DIM + lane * 2;
    float2 v = *(const float2*)(y + base);
    {
        float2 a = *(const float2*)(res + base);
        v.x += a.x; v.y += a.y;
    }
    if (res2) {
        float2 a = *(const float2*)(res2 + base);
        v.x += a.x; v.y += a.y;
    }
    if (res3) {
        float2 a = *(const float2*)(res3 + base);
        float2 c = *(const float2*)(res4 + base);
        v.x += a.x + c.x; v.y += a.y + c.y;
    }
    float s = v.x + v.y;
#pragma unroll
    for (int off = 32; off; off >>= 1) s += __shfl_xor(s, off, 64);
    const float mean = s * (1.f / 128.f);
    const float dx = v.x - mean, dy = v.y - mean;
    float q = dx * dx + dy * dy;
#pragma unroll
    for (int off = 32; off; off >>= 1) q += __shfl_xor(q, off, 64);
    const float rst = rsqrtf(q * (1.f / 128.f) + 1e-5f);
    const float2 gg = *(const float2*)(g + lane * 2);
    const float2 bb = *(const float2*)(b + lane * 2);
    float2 ov;
    ov.x = dx * rst * gg.x + bb.x;
    ov.y = dy * rst * gg.y + bb.y;
    *(float2*)(y + base) = ov;
    ushort2 pk;
    pk.x = f2b(ov.x);
    pk.y = f2b(ov.y);
    *(ushort2*)(yb + base) = pk;
}

// parallel mean-pool: grid (genre, 17 segments of 40 rows)
__global__ __launch_bounds__(256) void pool_partial(
    const float* __restrict__ y, const int* __restrict__ cnt, float* __restrict__ pooled)
{
    __shared__ float sh[128];
    const int g = blockIdx.x, seg = blockIdx.y, t = threadIdx.x;
    const int c = t & 127, h = t >> 7;
    const int L = cnt[g];
    const int k0 = seg * 40, k1 = min(k0 + 40, L);
    float s = 0.f;
    for (int k = k0 + h; k < k1; k += 2) s += y[((size_t)g * L_MAX + k) * DIM + c];
    if (h) sh[c] = s;
    __syncthreads();
    if (!h) {
        float tot = s + sh[c];
        if (k0 < L) atomicAdd(&pooled[g * DIM + c], tot / (float)max(L, 1));
    }
}

__global__ void build_fin(const float* __restrict__ acc, const float* __restrict__ pooled,
                          const int* __restrict__ midx, const int* __restrict__ genre,
                          ushort* __restrict__ A2)
{
    const int i = blockIdx.x, t = threadIdx.x;
    float v = (t < 128) ? acc[(size_t)midx[i] * DIM + t]
                        : pooled[genre[i] * DIM + (t - 128)];
    A2[(size_t)i * 256 + t] = f2b(v);
}

__global__ void scatter_movies(const float* __restrict__ fused, const int* __restrict__ midx,
                               float* __restrict__ out)
{
    const int i = blockIdx.x, c = threadIdx.x;
    out[(size_t)midx[i] * DIM + c] = fused[(size_t)i * DIM + c];
}

extern "C" void kernel_launch(void* const* d_in, const int* in_sizes, int n_in,
                              void* d_out, int out_size, void* d_ws, size_t ws_size,
                              hipStream_t stream)
{
    const float* x      = (const float*)d_in[0];
    const int* e[3]     = { (const int*)d_in[1], (const int*)d_in[2], (const int*)d_in[3] };
    const int* midx     = (const int*)d_in[4];
    const int* genre    = (const int*)d_in[5];
    const float* gatW   = (const float*)d_in[6];
    const float* attS   = (const float*)d_in[7];
    const float* attD   = (const float*)d_in[8];
    const float* gatB   = (const float*)d_in[9];
    const float* decW   = (const float*)d_in[10];
    const float* decB   = (const float*)d_in[11];
    const float* qkvW   = (const float*)d_in[12];
    const float* qkvB   = (const float*)d_in[13];
    const float* outW   = (const float*)d_in[14];
    const float* outB   = (const float*)d_in[15];
    const float* ln1g   = (const float*)d_in[16];
    const float* ln1b   = (const float*)d_in[17];
    const float* ln2g   = (const float*)d_in[18];
    const float* ln2b   = (const float*)d_in[19];
    const float* fw1    = (const float*)d_in[20];
    const float* fb1    = (const float*)d_in[21];
    const float* fw2    = (const float*)d_in[22];
    const float* fb2    = (const float*)d_in[23];
    const float* fusW   = (const float*)d_in[24];
    const float* fusB   = (const float*)d_in[25];
    float* out = (float*)d_out;

    // ---- workspace layout ----
    float* ws  = (float*)d_ws;
    float* acc = out;                             // final node features live in d_out
    float* R   = ws + 6400000;
    // stage A (ws low region + R):
    ushort* xb   = (ushort*)(ws);                 // 6.4M shorts
    ushort* gatWb= (ushort*)(ws + 3200000);       // 49,152 shorts
    ushort* decWb= (ushort*)(ws + 3224576);       // 49,152 shorts
    float*  als3 = ws + 3249152;                  // 600,000
    float*  ald3 = ws + 3849152;                  // 600,000
    int*    off3 = (int*)(ws + 4449152);          // 150,000
    int*    deg3 = (int*)(ws + 4599152);          // 150,000
    ushort* hb3  = (ushort*)(R);                  // 3 x 6.4M shorts
    ushort* gbx3 = (ushort*)(R + 9600000);        // 3 x 6.4M shorts
    int*   bcur  = (int*)(R + 19200000);          // 4,704 (3*98 x 16-int lines)
    int*   ebuf  = (int*)(R + 19204736);          // 1,354,752
    int*   srcs3 = (int*)(R + 20559488);          // 1,505,280 -> ends R+22,064,768
    // stage B (aliases stage A's R region):
    float*  ybuf  = R;                            // 2,611,200
    float*  tmp   = R + 2611200;                  // 2,611,200
    ushort* ybx   = (ushort*)(R + 5222400);       // 2,611,200 shorts
    ushort* attnb = (ushort*)(R + 6528000);       // 2,611,200 shorts
    ushort* qkvb  = (ushort*)(R + 7833600);       // 5,222,400 shorts (Q,K stride 256)
    ushort* vtg   = (ushort*)(R + 10444800);      // 2,611,200 shorts (V^T [128][20400])
    ushort* finb  = (ushort*)(R + 11750400);      // 5,222,400 shorts
    float*  tmp2  = R + 14361600;                 // 2,611,200 (FFN partial q1)
    float*  tmp3  = R + 16972800;                 // 2,611,200 (FFN partial q2)
    float*  tmp4  = R + 19584000;                 // 2,611,200 (FFN partial q3)
    float*  pooled= R + 22195200;                 // 3,840
    int*    cntb  = (int*)(R + 22199040);         // 32
    int*    posb  = cntb + 32;                    // 20,400
    ushort* qkvWb = (ushort*)(R + 22220000);      // 196,608 shorts
    ushort* outWb = (ushort*)(R + 22318304);      // 65,536 shorts
    ushort* fw1b  = (ushort*)(R + 22351072);      // 1,048,576 shorts
    ushort* fw2b  = (ushort*)(R + 22875360);      // 1,048,576 shorts
    ushort* fusWb = (ushort*)(R + 23399648);      // 32,768 shorts

    // ================= weight conversions (one launch) + x =================
    cvt_w<<<dim3(512, 7), 256, 0, stream>>>(
        gatW, decW, qkvW, outW, fw1, fw2, fusW,
        gatWb, decWb, qkvWb, outWb, fw1b, fw2b, fusWb);
    cvt32<<<(6400000 / 8 + 255) / 256, 256, 0, stream>>>(x, xb, 6400000 / 8);

    // ================= bucketed CSR build (all 3 hops) =================
    csr_initb<<<(3 * NBKT + 255) / 256, 256, 0, stream>>>(bcur);
    csr_route<<<dim3((N_EDGES + 4095) / 4096, 3), 256, 0, stream>>>(
        e[0], e[1], e[2], bcur, ebuf);
    csr_build<<<dim3(NBKT, 3), 256, 0, stream>>>(bcur, ebuf, off3, deg3, srcs3);

    // ================= Stage A: 3-hop GAT (hop-merged launches) =================
    gemm_lds<128, 0, 0, 1><<<dim3(391, 1, 3), 256, 0, stream>>>(
        xb, gatWb, nullptr, hb3, N_NODES, DIM, DIM, 1.f,
        (size_t)DIM * DIM, (size_t)N_NODES * DIM);
    gat_al<<<dim3((N_NODES * 4 + 255) / 256, 3), 256, 0, stream>>>(
        hb3, attS, attD, als3, ald3, N_NODES);
    gat_gather<<<dim3(N_NODES * 64 / 256, 3), 256, 0, stream>>>(
        off3, deg3, srcs3, hb3, als3, ald3, gatB, gbx3);
    dec3_gemm<<<391, 256, 0, stream>>>(gbx3, decWb, decB, acc, N_NODES);

    // ================= Stage B: genre transformer =================
    hipMemsetAsync(cntb, 0, 32 * 4, stream);
    calc_pos<<<(N_MOVIE + 255) / 256, 256, 0, stream>>>(genre, posb, cntb, N_MOVIE);
    build_y<<<N_MOVIE, 128, 0, stream>>>(acc, midx, genre, posb, ybuf, ybx);

    for (int l = 0; l < N_LAYERS; l++) {
        qkv_gemm<<<dim3(160, 3), 256, 0, stream>>>(
            ybx, qkvWb + (size_t)l * 384 * DIM, qkvB + l * 384, qkvb, vtg, NROWS);
        flash_attn<<<dim3(6, 4, 30), 256, 0, stream>>>(qkvb, vtg, cntb, attnb);
        proj_ln<<<(NROWS + 63) / 64, 256, 0, stream>>>(
            attnb, outWb + (size_t)l * DIM * DIM, outB + l * DIM,
            ybuf, ln1g + l * DIM, ln1b + l * DIM, ybx, NROWS);
        ffn_fused<<<dim3((NROWS + 127) / 128, 4), 256, 0, stream>>>(
            ybx, fw1b + (size_t)l * FF * DIM, fb1 + (size_t)l * FF,
            fw2b + (size_t)l * DIM * FF, fb2 + (size_t)l * DIM,
            tmp, tmp2, tmp3, tmp4, NROWS);
        ln_res<<<NROWS / 4, 256, 0, stream>>>(ybuf, tmp, tmp2, tmp3, tmp4,
                                              ln2g + l * DIM, ln2b + l * DIM, ybx);
    }

    hipMemsetAsync(pooled, 0, 3840 * 4, stream);
    pool_partial<<<dim3(N_GENRE, 17), 256, 0, stream>>>(ybuf, cntb, pooled);
    build_fin<<<N_MOVIE, 256, 0, stream>>>(acc, pooled, midx, genre, finb);
    gemm_lds<64, 1, 0, 0><<<dim3(319, 1, 1), 256, 0, stream>>>(
        finb, fusWb, fusB, tmp, NROWS, DIM, 256, 1.f, 0, 0);

    scatter_movies<<<N_MOVIE, 128, 0, stream>>>(tmp, midx, out);
}

// Round 10
// 815.729 us; speedup vs baseline: 1.0223x; 1.0223x over previous
//
#include <hip/hip_runtime.h>

#define N_NODES  50000
#define N_EDGES  400000
#define DIM      128
#define N_MOVIE  20400
#define N_GENRE  30
#define L_MAX    680
#define NROWS    (N_GENRE * L_MAX)   /* 20400 */
#define FF       2048
#define N_LAYERS 4

// bucketed CSR build
#define NBKT 98          /* bucket = dst >> 9 (512 nodes per bucket) */
#define NPB  512
#define ECAP 4608        /* edges per bucket capacity (mean 4096 + 8 sigma) */
#define SCAP 5120        /* CSR per bucket capacity (edges + selfs) */
#define EPGB (NBKT * ECAP)
#define SPGB (NBKT * SCAP)

typedef __attribute__((ext_vector_type(8))) short bf16x8;
typedef __attribute__((ext_vector_type(4))) float f32x4;

#define MFMA16 __builtin_amdgcn_mfma_f32_16x16x32_bf16

__device__ __forceinline__ float b2f(ushort u) {
    union { unsigned i; float f; } c; c.i = ((unsigned)u) << 16; return c.f;
}
__device__ __forceinline__ ushort f2b(float f) {
    union { float f; unsigned i; } c; c.f = f;
    unsigned u = c.i;
    u += 0x7FFFu + ((u >> 16) & 1u);   // RNE
    return (ushort)(u >> 16);
}
__device__ __forceinline__ bf16x8 load8s(const ushort* p) {
    return *(const bf16x8*)p;
}
__device__ __forceinline__ void async16(const ushort* g, ushort* l) {
    __builtin_amdgcn_global_load_lds(
        (const __attribute__((address_space(1))) void*)g,
        (__attribute__((address_space(3))) void*)l, 16, 0, 0);
}

__device__ __forceinline__ void cvt8(const float* s, ushort* d, int i) {
    const float4* q = (const float4*)(s + (size_t)i * 8);
    float4 a = q[0], b = q[1];
    bf16x8 r;
    r[0] = (short)f2b(a.x); r[1] = (short)f2b(a.y);
    r[2] = (short)f2b(a.z); r[3] = (short)f2b(a.w);
    r[4] = (short)f2b(b.x); r[5] = (short)f2b(b.y);
    r[6] = (short)f2b(b.z); r[7] = (short)f2b(b.w);
    *(bf16x8*)(d + (size_t)i * 8) = r;
}

// fp32 -> bf16, 8 elems/thread
__global__ void cvt32(const float* __restrict__ s, ushort* __restrict__ d, int n8)
{
    int i = blockIdx.x * blockDim.x + threadIdx.x;
    if (i < n8) cvt8(s, d, i);
}

// all 7 weight tensors in one launch (blockIdx.y selects tensor)
__global__ void cvt_w(const float* gatW, const float* decW, const float* qkvW,
                      const float* outW, const float* fw1, const float* fw2,
                      const float* fusW,
                      ushort* gatWb, ushort* decWb, ushort* qkvWb,
                      ushort* outWb, ushort* fw1b, ushort* fw2b, ushort* fusWb)
{
    const float* s; ushort* d; int n8;
    switch (blockIdx.y) {
        case 0: s = gatW; d = gatWb; n8 = 49152 / 8; break;
        case 1: s = decW; d = decWb; n8 = 49152 / 8; break;
        case 2: s = qkvW; d = qkvWb; n8 = 196608 / 8; break;
        case 3: s = outW; d = outWb; n8 = 65536 / 8; break;
        case 4: s = fw1;  d = fw1b;  n8 = 1048576 / 8; break;
        case 5: s = fw2;  d = fw2b;  n8 = 1048576 / 8; break;
        default: s = fusW; d = fusWb; n8 = 32768 / 8; break;
    }
    int i = blockIdx.x * 256 + threadIdx.x;
    if (i < n8) cvt8(s, d, i);
}

// ============ LDS-staged GEMM v2: full K=128 panel per stage ============
// C[M,N] = epi(A @ W^T + bias). K multiple of 128. XOR segment swizzle both-sides.
// blockIdx.z = slice index: W += z*wstride, OBF1 out += z*cstride.
// OBF: 0 = f32 out, 1 = bf16 out (LDS-staged coalesced write, BM=128 only).
template<int BM, int ACT, int EPI, int OBF>
__global__ __launch_bounds__(256) void gemm_lds(
    const ushort* __restrict__ A, const ushort* __restrict__ W_,
    const float* __restrict__ bias, void* __restrict__ Cv,
    int M, int N, int K, float scale, size_t wstride, size_t cstride)
{
    __shared__ ushort smem[BM * 128 + 128 * 128];
    ushort* As = smem;
    ushort* Ws = smem + BM * 128;
    const int tid  = threadIdx.x;
    const int wave = tid >> 6, lane = tid & 63;
    const int quad = lane >> 4, l16 = lane & 15;
    const int m0 = blockIdx.x * BM;
    const int n0 = blockIdx.y * 128;
    const int hop = blockIdx.z;
    const ushort* W = W_ + (size_t)hop * wstride;

    constexpr int MT = BM / 32;
    const int mbase = (wave & 1) * (BM / 2);
    const int nbase = (wave >> 1) * 64;

    f32x4 acc[MT][4] = {};
    for (int k0 = 0; k0 < K; k0 += 128) {
        if (k0) __syncthreads();
#pragma unroll
        for (int i = 0; i < BM / 16; i++) {
            int seg = i * 256 + tid;
            int r = seg >> 4, s = seg & 15;
            int rg = min(m0 + r, M - 1);
            async16(A + (size_t)rg * K + k0 + ((s ^ (r & 15)) * 8),
                    As + r * 128 + s * 8);
        }
#pragma unroll
        for (int i = 0; i < 8; i++) {
            int seg = i * 256 + tid;
            int r = seg >> 4, s = seg & 15;
            async16(W + (size_t)(n0 + r) * K + k0 + ((s ^ (r & 15)) * 8),
                    Ws + r * 128 + s * 8);
        }
        __syncthreads();

#pragma unroll
        for (int kk = 0; kk < 4; kk++) {
            bf16x8 a[MT], b[4];
#pragma unroll
            for (int mt = 0; mt < MT; mt++)
                a[mt] = load8s(As + (mbase + mt * 16 + l16) * 128 +
                               (((kk * 4 + quad) ^ l16) * 8));
#pragma unroll
            for (int nt = 0; nt < 4; nt++)
                b[nt] = load8s(Ws + (nbase + nt * 16 + l16) * 128 +
                               (((kk * 4 + quad) ^ l16) * 8));
#pragma unroll
            for (int mt = 0; mt < MT; mt++)
#pragma unroll
                for (int nt = 0; nt < 4; nt++)
                    acc[mt][nt] = MFMA16(a[mt], b[nt], acc[mt][nt], 0, 0, 0);
        }
    }

    if constexpr (OBF == 1) {
        static_assert(BM == 128, "OBF=1 staged epilogue assumes BM=128");
        ushort* Cs = smem;
        __syncthreads();
#pragma unroll
        for (int p = 0; p < 2; p++) {
            if ((wave & 1) == p) {
#pragma unroll
                for (int nt = 0; nt < 4; nt++) {
                    const int col = nbase + nt * 16 + l16;
                    const float bv = bias ? bias[n0 + col] : 0.f;
#pragma unroll
                    for (int mt = 0; mt < MT; mt++) {
                        const int rl = mt * 16 + quad * 4;
#pragma unroll
                        for (int r = 0; r < 4; r++) {
                            float v = acc[mt][nt][r] + bv;
                            if (ACT == 1) v = (v >= 0.f) ? v : 0.01f * v;
                            if (ACT == 2) v = fmaxf(v, 0.f);
                            Cs[(rl + r) * 128 + col] = f2b(v);
                        }
                    }
                }
            }
            __syncthreads();
            const int row = tid >> 2, cb = (tid & 3) * 32;   // 32 shorts = 64B
            const int grow = m0 + p * 64 + row;
            if (grow < M) {
                const ushort* s = Cs + row * 128 + cb;
                ushort* dp = (ushort*)Cv + (size_t)hop * cstride +
                             (size_t)grow * N + n0 + cb;
                *(int4*)(dp)      = *(const int4*)(s);
                *(int4*)(dp + 8)  = *(const int4*)(s + 8);
                *(int4*)(dp + 16) = *(const int4*)(s + 16);
                *(int4*)(dp + 24) = *(const int4*)(s + 24);
            }
            __syncthreads();
        }
    } else {
#pragma unroll
        for (int nt = 0; nt < 4; nt++) {
            const int col = n0 + nbase + nt * 16 + l16;
            const float bv = bias ? bias[col] : 0.f;
#pragma unroll
            for (int mt = 0; mt < MT; mt++) {
#pragma unroll
                for (int r = 0; r < 4; r++) {
                    const int row = m0 + mbase + mt * 16 + quad * 4 + r;
                    if (row < M) {
                        float v = acc[mt][nt][r] + bv;
                        if (ACT == 1) v = (v >= 0.f) ? v : 0.01f * v;
                        if (ACT == 2) v = fmaxf(v, 0.f);
                        const size_t idx = (size_t)row * N + col;
                        if (EPI == 1) ((float*)Cv)[idx] += scale * v;
                        else          ((float*)Cv)[idx] = v;
                    }
                }
            }
        }
    }
}

// ====== merged 3-hop decoder GEMM: acc = sum_k decay_k*leaky(gbx_k@decW_k^T+b_k) ======
__global__ __launch_bounds__(256) void dec3_gemm(
    const ushort* __restrict__ gbx3, const ushort* __restrict__ decWb,
    const float* __restrict__ decB, float* __restrict__ outp, int M)
{
    __shared__ ushort smem[2 * 128 * 128];   // 64 KB
    ushort* As = smem;
    ushort* Ws = smem + 128 * 128;
    const int tid  = threadIdx.x;
    const int wave = tid >> 6, lane = tid & 63;
    const int quad = lane >> 4, l16 = lane & 15;
    const int m0 = blockIdx.x * 128;
    const int mbase = (wave & 1) * 64;
    const int nbase = (wave >> 1) * 64;
    const float decay[3] = { 1.0f, 0.90483741803595952f, 0.81873075307798182f };

    float fac[4][4][4] = {};
    for (int hop = 0; hop < 3; hop++) {
        if (hop) __syncthreads();
        const ushort* A = gbx3 + (size_t)hop * M * DIM;
        const ushort* W = decWb + hop * DIM * DIM;
#pragma unroll
        for (int i = 0; i < 8; i++) {
            int seg = i * 256 + tid;
            int r = seg >> 4, s = seg & 15;
            int rg = min(m0 + r, M - 1);
            async16(A + (size_t)rg * 128 + ((s ^ (r & 15)) * 8), As + r * 128 + s * 8);
        }
#pragma unroll
        for (int i = 0; i < 8; i++) {
            int seg = i * 256 + tid;
            int r = seg >> 4, s = seg & 15;
            async16(W + (size_t)r * 128 + ((s ^ (r & 15)) * 8), Ws + r * 128 + s * 8);
        }
        __syncthreads();
        f32x4 acc[4][4] = {};
#pragma unroll
        for (int kk = 0; kk < 4; kk++) {
            bf16x8 a[4], b[4];
#pragma unroll
            for (int mt = 0; mt < 4; mt++)
                a[mt] = load8s(As + (mbase + mt * 16 + l16) * 128 +
                               (((kk * 4 + quad) ^ l16) * 8));
#pragma unroll
            for (int nt = 0; nt < 4; nt++)
                b[nt] = load8s(Ws + (nbase + nt * 16 + l16) * 128 +
                               (((kk * 4 + quad) ^ l16) * 8));
#pragma unroll
            for (int mt = 0; mt < 4; mt++)
#pragma unroll
                for (int nt = 0; nt < 4; nt++)
                    acc[mt][nt] = MFMA16(a[mt], b[nt], acc[mt][nt], 0, 0, 0);
        }
        const float dk = decay[hop];
#pragma unroll
        for (int nt = 0; nt < 4; nt++) {
            const int col = nbase + nt * 16 + l16;
            const float bv = decB[hop * DIM + col];
#pragma unroll
            for (int mt = 0; mt < 4; mt++)
#pragma unroll
                for (int r = 0; r < 4; r++) {
                    float v = acc[mt][nt][r] + bv;
                    v = (v >= 0.f) ? v : 0.01f * v;
                    fac[mt][nt][r] += dk * v;
                }
        }
    }
#pragma unroll
    for (int nt = 0; nt < 4; nt++) {
        const int col = nbase + nt * 16 + l16;
#pragma unroll
        for (int mt = 0; mt < 4; mt++)
#pragma unroll
            for (int r = 0; r < 4; r++) {
                const int row = m0 + mbase + mt * 16 + quad * 4 + r;
                if (row < M) outp[(size_t)row * 128 + col] = fac[mt][nt][r];
            }
    }
}

// ====== fused out-proj + residual + LayerNorm (post-LN attn branch) ======
__global__ __launch_bounds__(256) void proj_ln(
    const ushort* __restrict__ A, const ushort* __restrict__ W,
    const float* __restrict__ bias, float* __restrict__ y,
    const float* __restrict__ g, const float* __restrict__ b,
    ushort* __restrict__ yb, int M)
{
    __shared__ ushort smem[64 * 128 + 128 * 128];   // 48 KB
    __shared__ float lnsum[64][2], lnsq[64][2];
    ushort* As = smem;
    ushort* Ws = smem + 64 * 128;
    const int tid  = threadIdx.x;
    const int wave = tid >> 6, lane = tid & 63;
    const int quad = lane >> 4, l16 = lane & 15;
    const int m0 = blockIdx.x * 64;
    const int mbase = (wave & 1) * 32;
    const int nbase = (wave >> 1) * 64;
    const int half = wave >> 1;

#pragma unroll
    for (int i = 0; i < 4; i++) {
        int seg = i * 256 + tid;
        int r = seg >> 4, s = seg & 15;
        int rg = min(m0 + r, M - 1);
        async16(A + (size_t)rg * 128 + ((s ^ (r & 15)) * 8), As + r * 128 + s * 8);
    }
#pragma unroll
    for (int i = 0; i < 8; i++) {
        int seg = i * 256 + tid;
        int r = seg >> 4, s = seg & 15;
        async16(W + (size_t)r * 128 + ((s ^ (r & 15)) * 8), Ws + r * 128 + s * 8);
    }
    __syncthreads();

    f32x4 acc[2][4] = {};
#pragma unroll
    for (int kk = 0; kk < 4; kk++) {
        bf16x8 a[2], bfr[4];
#pragma unroll
        for (int mt = 0; mt < 2; mt++)
            a[mt] = load8s(As + (mbase + mt * 16 + l16) * 128 +
                           (((kk * 4 + quad) ^ l16) * 8));
#pragma unroll
        for (int nt = 0; nt < 4; nt++)
            bfr[nt] = load8s(Ws + (nbase + nt * 16 + l16) * 128 +
                             (((kk * 4 + quad) ^ l16) * 8));
#pragma unroll
        for (int mt = 0; mt < 2; mt++)
#pragma unroll
            for (int nt = 0; nt < 4; nt++)
                acc[mt][nt] = MFMA16(a[mt], bfr[nt], acc[mt][nt], 0, 0, 0);
    }

    // residual add + row partial sums
    float vv[2][4][4];
    float rs[2][4] = {};
#pragma unroll
    for (int mt = 0; mt < 2; mt++)
#pragma unroll
        for (int nt = 0; nt < 4; nt++) {
            const int col = nbase + nt * 16 + l16;
            const float bv = bias[col];
#pragma unroll
            for (int rr = 0; rr < 4; rr++) {
                const int row = m0 + mbase + mt * 16 + quad * 4 + rr;
                float v = acc[mt][nt][rr] + bv;
                if (row < M) v += y[(size_t)row * 128 + col];
                vv[mt][nt][rr] = v;
                rs[mt][rr] += v;
            }
        }
#pragma unroll
    for (int mt = 0; mt < 2; mt++)
#pragma unroll
        for (int rr = 0; rr < 4; rr++) {
#pragma unroll
            for (int off = 1; off <= 8; off <<= 1)
                rs[mt][rr] += __shfl_xor(rs[mt][rr], off, 64);
            if (l16 == 0)
                lnsum[mbase + mt * 16 + quad * 4 + rr][half] = rs[mt][rr];
        }
    __syncthreads();

    float mean[2][4];
#pragma unroll
    for (int mt = 0; mt < 2; mt++)
#pragma unroll
        for (int rr = 0; rr < 4; rr++) {
            const int rl = mbase + mt * 16 + quad * 4 + rr;
            mean[mt][rr] = (lnsum[rl][0] + lnsum[rl][1]) * (1.f / 128.f);
            float q = 0.f;
#pragma unroll
            for (int nt = 0; nt < 4; nt++) {
                float d = vv[mt][nt][rr] - mean[mt][rr];
                q += d * d;
            }
#pragma unroll
            for (int off = 1; off <= 8; off <<= 1)
                q += __shfl_xor(q, off, 64);
            if (l16 == 0) lnsq[rl][half] = q;
        }
    __syncthreads();

#pragma unroll
    for (int mt = 0; mt < 2; mt++)
#pragma unroll
        for (int rr = 0; rr < 4; rr++) {
            const int rl = mbase + mt * 16 + quad * 4 + rr;
            const int row = m0 + rl;
            const float rstd = rsqrtf((lnsq[rl][0] + lnsq[rl][1]) * (1.f / 128.f) + 1e-5f);
            if (row < M) {
#pragma unroll
                for (int nt = 0; nt < 4; nt++) {
                    const int col = nbase + nt * 16 + l16;
                    float o = (vv[mt][nt][rr] - mean[mt][rr]) * rstd * g[col] + b[col];
                    y[(size_t)row * 128 + col] = o;
                    yb[(size_t)row * 128 + col] = f2b(o);
                }
            }
        }
}

// ====== merged QKV + V^T GEMM: grid (160, 3) ======
__global__ __launch_bounds__(256) void qkv_gemm(
    const ushort* __restrict__ A, const ushort* __restrict__ W0,
    const float* __restrict__ bias0, ushort* __restrict__ qkv,
    ushort* __restrict__ vt, int M)
{
    __shared__ ushort smem[2 * 128 * 128];
    ushort* As = smem;
    ushort* Ws = smem + 128 * 128;
    const int tid  = threadIdx.x;
    const int wave = tid >> 6, lane = tid & 63;
    const int quad = lane >> 4, l16 = lane & 15;
    const int m0 = blockIdx.x * 128;
    const int sel = blockIdx.y;
    const ushort* W = W0 + (size_t)sel * 128 * 128;
    const int mbase = (wave & 1) * 64;
    const int nbase = (wave >> 1) * 64;

    f32x4 acc[4][4] = {};
#pragma unroll
    for (int i = 0; i < 8; i++) {
        int seg = i * 256 + tid;
        int r = seg >> 4, s = seg & 15;
        int rg = min(m0 + r, M - 1);
        async16(A + (size_t)rg * 128 + ((s ^ (r & 15)) * 8), As + r * 128 + s * 8);
    }
#pragma unroll
    for (int i = 0; i < 8; i++) {
        int seg = i * 256 + tid;
        int r = seg >> 4, s = seg & 15;
        async16(W + (size_t)r * 128 + ((s ^ (r & 15)) * 8), Ws + r * 128 + s * 8);
    }
    __syncthreads();
#pragma unroll
    for (int kk = 0; kk < 4; kk++) {
        bf16x8 a[4], b[4];
#pragma unroll
        for (int mt = 0; mt < 4; mt++)
            a[mt] = load8s(As + (mbase + mt * 16 + l16) * 128 +
                           (((kk * 4 + quad) ^ l16) * 8));
#pragma unroll
        for (int nt = 0; nt < 4; nt++)
            b[nt] = load8s(Ws + (nbase + nt * 16 + l16) * 128 +
                           (((kk * 4 + quad) ^ l16) * 8));
#pragma unroll
        for (int mt = 0; mt < 4; mt++)
#pragma unroll
            for (int nt = 0; nt < 4; nt++)
                acc[mt][nt] = MFMA16(a[mt], b[nt], acc[mt][nt], 0, 0, 0);
    }

    if (sel < 2) {
        ushort* Cs = smem;
        __syncthreads();
#pragma unroll
        for (int p = 0; p < 2; p++) {
            if ((wave & 1) == p) {
#pragma unroll
                for (int nt = 0; nt < 4; nt++) {
                    const int col = nbase + nt * 16 + l16;
                    const float bv = bias0[sel * 128 + col];
#pragma unroll
                    for (int mt = 0; mt < 4; mt++) {
                        const int rl = mt * 16 + quad * 4;
#pragma unroll
                        for (int r = 0; r < 4; r++)
                            Cs[(rl + r) * 128 + col] = f2b(acc[mt][nt][r] + bv);
                    }
                }
            }
            __syncthreads();
            const int row = tid >> 2, cb = (tid & 3) * 32;
            const int grow = m0 + p * 64 + row;
            if (grow < M) {
                const ushort* s = Cs + row * 128 + cb;
                ushort* dp = qkv + (size_t)grow * 256 + sel * 128 + cb;
                *(int4*)(dp)      = *(const int4*)(s);
                *(int4*)(dp + 8)  = *(const int4*)(s + 8);
                *(int4*)(dp + 16) = *(const int4*)(s + 16);
                *(int4*)(dp + 24) = *(const int4*)(s + 24);
            }
            __syncthreads();
        }
    } else {
#pragma unroll
        for (int nt = 0; nt < 4; nt++) {
            const int col = nbase + nt * 16 + l16;
            const float bv = bias0[256 + col];
#pragma unroll
            for (int mt = 0; mt < 4; mt++) {
                const int row0 = m0 + mbase + mt * 16 + quad * 4;
                if (row0 < M) {
                    ushort4 pk;
                    pk.x = f2b(acc[mt][nt][0] + bv);
                    pk.y = f2b(acc[mt][nt][1] + bv);
                    pk.z = f2b(acc[mt][nt][2] + bv);
                    pk.w = f2b(acc[mt][nt][3] + bv);
                    *(ushort4*)(vt + (size_t)col * M + row0) = pk;
                }
            }
        }
    }
}

// ====== Fused FFN (R4-proven): LDS-staged weights, 4 FF-quarters ======
__global__ __launch_bounds__(256, 2) void ffn_fused(
    const ushort* __restrict__ y, const ushort* __restrict__ w1,
    const float* __restrict__ b1, const ushort* __restrict__ w2,
    const float* __restrict__ b2,
    float* __restrict__ o0, float* __restrict__ o1,
    float* __restrict__ o2, float* __restrict__ o3, int M)
{
    __shared__ ushort f1s[2][32 * 128];   // 2x8 KB
    __shared__ ushort f2s[2][128 * 32];   // 2x8 KB
    __shared__ ushort mids[4][32 * 40];   // 10 KB wave-private
    const int tid  = threadIdx.x;
    const int wave = tid >> 6, lane = tid & 63;
    const int quad = lane >> 4, l16 = lane & 15;
    const int m0 = blockIdx.x * 128;
    const int fh = blockIdx.y;
    const int fbase = fh * (FF / 4);
    float* o = (fh == 0) ? o0 : (fh == 1) ? o1 : (fh == 2) ? o2 : o3;

    const int sw1 = ((tid & 15) ^ (tid >> 4)) * 8;
    const int sw2 = ((tid & 3) ^ ((tid >> 3) & 3)) * 8;

    const int wrow = m0 + wave * 32;
    bf16x8 yf[2][4];
#pragma unroll
    for (int mt = 0; mt < 2; mt++) {
        const int mr = min(wrow + mt * 16 + l16, M - 1);
#pragma unroll
        for (int ks = 0; ks < 4; ks++)
            yf[mt][ks] = load8s(y + (size_t)mr * 128 + ks * 32 + quad * 8);
    }

#pragma unroll
    for (int i = 0; i < 2; i++) {
        int row = i * 16 + (tid >> 4);
        async16(w1 + (size_t)(fbase + row) * 128 + sw1,
                f1s[0] + row * 128 + (tid & 15) * 8);
    }
#pragma unroll
    for (int i = 0; i < 2; i++) {
        int row = i * 64 + (tid >> 2);
        async16(w2 + (size_t)row * FF + fbase + sw2,
                f2s[0] + row * 32 + (tid & 3) * 8);
    }

    f32x4 oacc[2][8] = {};
    ushort* midw = mids[wave];
    int cur = 0;
    __syncthreads();

    for (int fo = 0; fo < FF / 4; fo += 32) {
        if (fo + 32 < FF / 4) {
            const int fn = fbase + fo + 32;
#pragma unroll
            for (int i = 0; i < 2; i++) {
                int row = i * 16 + (tid >> 4);
                async16(w1 + (size_t)(fn + row) * 128 + sw1,
                        f1s[cur ^ 1] + row * 128 + (tid & 15) * 8);
            }
#pragma unroll
            for (int i = 0; i < 2; i++) {
                int row = i * 64 + (tid >> 2);
                async16(w2 + (size_t)row * FF + fn + sw2,
                        f2s[cur ^ 1] + row * 32 + (tid & 3) * 8);
            }
        }
        const ushort* F1 = f1s[cur];
        const ushort* F2 = f2s[cur];

        f32x4 midacc[2][2] = {};
#pragma unroll
        for (int ks = 0; ks < 4; ks++) {
            const int csA = (((ks * 4 + quad) ^ l16) & 15) * 8;
#pragma unroll
            for (int ft = 0; ft < 2; ft++) {
                bf16x8 wf = load8s(F1 + (ft * 16 + l16) * 128 + csA);
                midacc[0][ft] = MFMA16(wf, yf[0][ks], midacc[0][ft], 0, 0, 0);
                midacc[1][ft] = MFMA16(wf, yf[1][ks], midacc[1][ft], 0, 0, 0);
            }
        }
#pragma unroll
        for (int mt = 0; mt < 2; mt++)
#pragma unroll
            for (int ft = 0; ft < 2; ft++) {
                const float4 bb = *(const float4*)(b1 + fbase + fo + ft * 16 + quad * 4);
                ushort4 pk;
                pk.x = f2b(fmaxf(midacc[mt][ft][0] + bb.x, 0.f));
                pk.y = f2b(fmaxf(midacc[mt][ft][1] + bb.y, 0.f));
                pk.z = f2b(fmaxf(midacc[mt][ft][2] + bb.z, 0.f));
                pk.w = f2b(fmaxf(midacc[mt][ft][3] + bb.w, 0.f));
                *(ushort4*)(midw + (mt * 16 + l16) * 40 + ft * 16 + quad * 4) = pk;
            }
        bf16x8 mf0 = load8s(midw + (size_t)l16 * 40 + quad * 8);
        bf16x8 mf1 = load8s(midw + (size_t)(16 + l16) * 40 + quad * 8);
        const int gB = (quad ^ ((l16 >> 1) & 3)) * 8;
#pragma unroll
        for (int dt = 0; dt < 8; dt++) {
            bf16x8 wf = load8s(F2 + (dt * 16 + l16) * 32 + gB);
            oacc[0][dt] = MFMA16(wf, mf0, oacc[0][dt], 0, 0, 0);
            oacc[1][dt] = MFMA16(wf, mf1, oacc[1][dt], 0, 0, 0);
        }
        __syncthreads();
        cur ^= 1;
    }

#pragma unroll
    for (int mt = 0; mt < 2; mt++) {
        const int m = wrow + mt * 16 + l16;
        if (m < M) {
            float* op = o + (size_t)m * 128 + quad * 4;
#pragma unroll
            for (int dt = 0; dt < 8; dt++) {
                float4 v;
                if (fh == 0) {
                    const float4 bv = *(const float4*)(b2 + dt * 16 + quad * 4);
                    v.x = oacc[mt][dt][0] + bv.x;
                    v.y = oacc[mt][dt][1] + bv.y;
                    v.z = oacc[mt][dt][2] + bv.z;
                    v.w = oacc[mt][dt][3] + bv.w;
                } else {
                    v.x = oacc[mt][dt][0];
                    v.y = oacc[mt][dt][1];
                    v.z = oacc[mt][dt][2];
                    v.w = oacc[mt][dt][3];
                }
                *(float4*)(op + dt * 16) = v;
            }
        }
    }
}

// per-(node,head) attention logits, all 3 hops in one launch (blockIdx.y = hop)
__global__ void gat_al(const ushort* __restrict__ hb3,
                       const float* __restrict__ asrc, const float* __restrict__ adst,
                       float* __restrict__ als3, float* __restrict__ ald3, int N)
{
    int idx = blockIdx.x * blockDim.x + threadIdx.x;
    if (idx >= N * 4) return;
    const int hop = blockIdx.y;
    const ushort* h = hb3 + (size_t)hop * N * DIM;
    const float* as_ = asrc + hop * DIM;
    const float* ad_ = adst + hop * DIM;
    int n = idx >> 2, hh = idx & 3;
    const ushort* hp = h + (size_t)n * DIM + hh * 32;
    float s = 0.f, d = 0.f;
#pragma unroll
    for (int q = 0; q < 4; q++) {
        bf16x8 hv = load8s(hp + q * 8);
#pragma unroll
        for (int c = 0; c < 8; c++) {
            float v = b2f((ushort)hv[c]);
            s += v * as_[hh * 32 + q * 8 + c];
            d += v * ad_[hh * 32 + q * 8 + c];
        }
    }
    als3[(size_t)hop * N * 4 + idx] = s;
    ald3[(size_t)hop * N * 4 + idx] = d;
}

// ---------------- bucketed CSR build ----------------
__global__ void csr_initb(int* __restrict__ bcur)
{
    int i = blockIdx.x * 256 + threadIdx.x;
    if (i < 3 * NBKT) bcur[i * 16] = (i % NBKT) * ECAP;
}

__global__ __launch_bounds__(256) void csr_route(
    const int* __restrict__ e0, const int* __restrict__ e1, const int* __restrict__ e2,
    int* __restrict__ bcur, int* __restrict__ ebuf)
{
    __shared__ int hist[NBKT], base[NBKT], cur[NBKT];
    const int g = blockIdx.y, t = threadIdx.x;
    const int* e = (g == 0) ? e0 : (g == 1) ? e1 : e2;
    const int i0 = blockIdx.x * 4096;
    for (int j = t; j < NBKT; j += 256) { hist[j] = 0; cur[j] = 0; }
    __syncthreads();
    unsigned pk[16]; int bk[16];
#pragma unroll
    for (int j = 0; j < 16; j++) {
        int i = i0 + j * 256 + t;
        if (i < N_EDGES) {
            int s = e[i], d = e[N_EDGES + i];
            bk[j] = d >> 9;
            pk[j] = (unsigned)s | ((unsigned)(d & 511) << 16);
            atomicAdd(&hist[bk[j]], 1);
        } else bk[j] = -1;
    }
    __syncthreads();
    for (int j = t; j < NBKT; j += 256)
        if (hist[j]) base[j] = atomicAdd(&bcur[(g * NBKT + j) * 16], hist[j]);
    __syncthreads();
#pragma unroll
    for (int j = 0; j < 16; j++)
        if (bk[j] >= 0) {
            int p = base[bk[j]] + atomicAdd(&cur[bk[j]], 1);
            ebuf[(size_t)g * EPGB + p] = (int)pk[j];
        }
}

__global__ __launch_bounds__(256) void csr_build(
    const int* __restrict__ bcur, const int* __restrict__ ebuf,
    int* __restrict__ off, int* __restrict__ deg, int* __restrict__ srcs)
{
    __shared__ int hist[NPB];
    __shared__ int part[256];
    const int g = blockIdx.y, b = blockIdx.x, t = threadIdx.x;
    const int nb0 = b * NPB;
    const int nn = min(NPB, N_NODES - nb0);
    const int cnt = bcur[(g * NBKT + b) * 16] - b * ECAP;
    const int* eb = ebuf + (size_t)g * EPGB + b * ECAP;

    for (int j = t; j < NPB; j += 256) hist[j] = (j < nn) ? 1 : 0;   // self-loop
    __syncthreads();
    for (int i = t; i < cnt; i += 256)
        atomicAdd(&hist[(eb[i] >> 16) & 511], 1);
    __syncthreads();

    int a0 = hist[t * 2], a1 = hist[t * 2 + 1];
    int sum = a0 + a1;
    part[t] = sum;
    __syncthreads();
    for (int d = 1; d < 256; d <<= 1) {
        int x = (t >= d) ? part[t - d] : 0;
        __syncthreads();
        part[t] += x;
        __syncthreads();
    }
    const int excl = part[t] - sum;
    __syncthreads();
    const int sb = b * SCAP;
    hist[t * 2]     = excl;
    hist[t * 2 + 1] = excl + a0;
    if (t * 2 < nn) {
        off[(size_t)g * N_NODES + nb0 + t * 2] = sb + excl;
        deg[(size_t)g * N_NODES + nb0 + t * 2] = a0;
    }
    if (t * 2 + 1 < nn) {
        off[(size_t)g * N_NODES + nb0 + t * 2 + 1] = sb + excl + a0;
        deg[(size_t)g * N_NODES + nb0 + t * 2 + 1] = a1;
    }
    __syncthreads();

    int* sg = srcs + (size_t)g * SPGB + sb;
    for (int i = t; i < cnt; i += 256) {
        int v = eb[i];
        int p = atomicAdd(&hist[(v >> 16) & 511], 1);
        sg[p] = v & 0xFFFF;
    }
    for (int j = t; j < nn; j += 256) {
        int p = atomicAdd(&hist[j], 1);
        sg[p] = nb0 + j;
    }
}

// one wave per dst, 4 edge-groups x 16 lanes, 2 edges per group per iteration
// (j and j+4; next pair's srcs prefetched). All 3 hops (blockIdx.y = hop).
__global__ __launch_bounds__(256) void gat_gather(
    const int* __restrict__ off3, const int* __restrict__ deg3,
    const int* __restrict__ srcs3, const ushort* __restrict__ hb3,
    const float* __restrict__ als3, const float* __restrict__ ald3,
    const float* __restrict__ bias3, ushort* __restrict__ gbx3)
{
    int w = (blockIdx.x * 256 + threadIdx.x) >> 6;
    int lane = threadIdx.x & 63;
    if (w >= N_NODES) return;
    const int hop = blockIdx.y;
    const int* off = off3 + (size_t)hop * N_NODES;
    const int* deg = deg3 + (size_t)hop * N_NODES;
    const int* srcs = srcs3 + (size_t)hop * SPGB;
    const ushort* hb = hb3 + (size_t)hop * N_NODES * DIM;
    const float* als = als3 + (size_t)hop * N_NODES * 4;
    const float* ald = ald3 + (size_t)hop * N_NODES * 4;
    const float* bias = bias3 + hop * DIM;
    ushort* ob = gbx3 + (size_t)hop * N_NODES * DIM;

    const int grp  = lane >> 4;
    const int l16  = lane & 15;
    const int head = l16 >> 2;
    const float adv = ald[(size_t)w * 4 + head];
    const int jb = off[w], dg = deg[w];

    float acc[8] = {};
    float wsum = 0.f;

    int j = grp;
    int s0 = (j < dg)     ? srcs[jb + j]     : 0;
    int s1 = (j + 4 < dg) ? srcs[jb + j + 4] : 0;
    while (j < dg) {
        const int jn = j + 8;
        const int sn0 = (jn < dg)     ? srcs[jb + jn]     : 0;
        const int sn1 = (jn + 4 < dg) ? srcs[jb + jn + 4] : 0;
        const bool has1 = (j + 4 < dg);
        // issue both row loads before the VALU chain (independent latencies)
        bf16x8 hv0 = load8s(hb + (size_t)s0 * DIM + l16 * 8);
        bf16x8 hv1 = load8s(hb + (size_t)s1 * DIM + l16 * 8);
        float e0 = als[(size_t)s0 * 4 + head] + adv;
        e0 = (e0 >= 0.f) ? e0 : 0.2f * e0;
        float e1 = als[(size_t)s1 * 4 + head] + adv;
        e1 = (e1 >= 0.f) ? e1 : 0.2f * e1;
        const float w0 = __expf(e0);
        const float w1 = has1 ? __expf(e1) : 0.f;
        wsum += w0 + w1;
#pragma unroll
        for (int c = 0; c < 8; c++)
            acc[c] += w0 * b2f((ushort)hv0[c]) + w1 * b2f((ushort)hv1[c]);
        j = jn; s0 = sn0; s1 = sn1;
    }

    wsum += __shfl_xor(wsum, 16, 64);
    wsum += __shfl_xor(wsum, 32, 64);
#pragma unroll
    for (int c = 0; c < 8; c++) {
        acc[c] += __shfl_xor(acc[c], 16, 64);
        acc[c] += __shfl_xor(acc[c], 32, 64);
    }

    if (grp == 0) {
        const float inv = 1.f / wsum;
        bf16x8 r;
#pragma unroll
        for (int c = 0; c < 8; c++)
            r[c] = (short)f2b(acc[c] * inv + bias[l16 * 8 + c]);
        *(bf16x8*)(ob + (size_t)w * DIM + l16 * 8) = r;
    }
}

__global__ void calc_pos(const int* __restrict__ genre, int* __restrict__ pos,
                         int* __restrict__ cnt, int NM)
{
    int i = blockIdx.x * blockDim.x + threadIdx.x;
    if (i < NM) pos[i] = atomicAdd(&cnt[genre[i]], 1);
}

__global__ void build_y(const float* __restrict__ acc, const int* __restrict__ midx,
                        const int* __restrict__ genre, const int* __restrict__ pos,
                        float* __restrict__ y, ushort* __restrict__ yb)
{
    int i = blockIdx.x, c = threadIdx.x;
    int g = genre[i], p = pos[i];
    float v = acc[(size_t)midx[i] * DIM + c];
    size_t o = ((size_t)g * L_MAX + p) * DIM + c;
    y[o] = v; yb[o] = f2b(v);
}

// ======== barrier-free flash attention: V^T pre-transposed in global ========
#define SP 40    /* P row stride in shorts (80 B, 16B-aligned) */

__global__ __launch_bounds__(256) void flash_attn(
    const ushort* __restrict__ qk, const ushort* __restrict__ vtg,
    const int* __restrict__ cnt, ushort* __restrict__ o)
{
    __shared__ ushort Pb[4][32 * SP];     // 10240 B, wave-private tiles

    const int qt = blockIdx.x, hh = blockIdx.y, g = blockIdx.z;
    const int t = threadIdx.x, wave = t >> 6, lane = t & 63;
    const int quad = lane >> 4, l16 = lane & 15;
    const int L = cnt[g];
    const float scale = 0.17677669529663687f;   // 1/sqrt(32)
    const ushort* base = qk + (size_t)g * L_MAX * 256;
    const ushort* vb0 = vtg + (size_t)(hh * 32 + l16) * NROWS + g * L_MAX;
    const ushort* vb1 = vb0 + (size_t)16 * NROWS;

    const int q0 = qt * 128 + wave * 32;
    bf16x8 a0 = load8s(base + (size_t)min(q0 + l16,      L_MAX - 1) * 256 + hh * 32 + quad * 8);
    bf16x8 a1 = load8s(base + (size_t)min(q0 + 16 + l16, L_MAX - 1) * 256 + hh * 32 + quad * 8);

    f32x4 oacc[2][2] = {};        // [dhalf][qhalf], O^T layout
    float rsum[2] = {0.f, 0.f};
    ushort* P = Pb[wave];

    for (int kt = 0; kt < 704; kt += 32) {
        bf16x8 b0 = load8s(base + (size_t)min(kt + l16,      L_MAX - 1) * 256 + 128 + hh * 32 + quad * 8);
        bf16x8 b1 = load8s(base + (size_t)min(kt + 16 + l16, L_MAX - 1) * 256 + 128 + hh * 32 + quad * 8);
        f32x4 z = {};
        f32x4 st00 = MFMA16(b0, a0, z, 0, 0, 0);   // S^T[k][q]
        f32x4 st01 = MFMA16(b0, a1, z, 0, 0, 0);
        f32x4 st10 = MFMA16(b1, a0, z, 0, 0, 0);
        f32x4 st11 = MFMA16(b1, a1, z, 0, 0, 0);

        const int kc0 = kt + quad * 4, kc1 = kt + 16 + quad * 4;
#pragma unroll
        for (int qh = 0; qh < 2; qh++) {
            const f32x4 sA = qh ? st01 : st00;
            const f32x4 sB = qh ? st11 : st10;
            float w[8];
#pragma unroll
            for (int r = 0; r < 4; r++) {
                w[r]     = (kc0 + r < L) ? __expf(sA[r] * scale) : 0.f;
                w[4 + r] = (kc1 + r < L) ? __expf(sB[r] * scale) : 0.f;
                rsum[qh] += w[r] + w[4 + r];
            }
            ushort4 pk0, pk1;
            pk0.x = f2b(w[0]); pk0.y = f2b(w[1]); pk0.z = f2b(w[2]); pk0.w = f2b(w[3]);
            pk1.x = f2b(w[4]); pk1.y = f2b(w[5]); pk1.z = f2b(w[6]); pk1.w = f2b(w[7]);
            *(ushort4*)(P + (qh * 16 + l16) * SP + quad * 4)      = pk0;
            *(ushort4*)(P + (qh * 16 + l16) * SP + 16 + quad * 4) = pk1;
        }
        bf16x8 p0 = load8s(P + (size_t)l16 * SP + quad * 8);
        bf16x8 p1 = load8s(P + (size_t)(16 + l16) * SP + quad * 8);
        bf16x8 v0 = load8s(vb0 + kt + quad * 8);
        bf16x8 v1 = load8s(vb1 + kt + quad * 8);
        oacc[0][0] = MFMA16(v0, p0, oacc[0][0], 0, 0, 0);
        oacc[0][1] = MFMA16(v0, p1, oacc[0][1], 0, 0, 0);
        oacc[1][0] = MFMA16(v1, p0, oacc[1][0], 0, 0, 0);
        oacc[1][1] = MFMA16(v1, p1, oacc[1][1], 0, 0, 0);
    }

#pragma unroll
    for (int qh = 0; qh < 2; qh++) {
        float s = rsum[qh];
        s += __shfl_xor(s, 16, 64);
        s += __shfl_xor(s, 32, 64);
        const int q = q0 + qh * 16 + l16;
        if (q < L_MAX) {
            const float inv = 1.f / s;
#pragma unroll
            for (int dh = 0; dh < 2; dh++) {
                ushort4 pk;
                pk.x = f2b(oacc[dh][qh][0] * inv);
                pk.y = f2b(oacc[dh][qh][1] * inv);
                pk.z = f2b(oacc[dh][qh][2] * inv);
                pk.w = f2b(oacc[dh][qh][3] * inv);
                *(ushort4*)(o + ((size_t)(g * L_MAX + q)) * DIM + hh * 32 + dh * 16 + quad * 4) = pk;
            }
        }
    }
}

// y = LN(y + res [+ res2 [+ res3 + res4]]) * g + b; wave-per-row, no LDS/barriers.
__global__ __launch_bounds__(256) void ln_res(
    float* __restrict__ y, const float* __restrict__ res,
    const float* __restrict__ res2, const float* __restrict__ res3,
    const float* __restrict__ res4,
    const float* __restrict__ g, const float* __restrict__ b,
    ushort* __restrict__ yb)
{
    const int r = blockIdx.x * 4 + (threadIdx.x >> 6);
    const int lane = threadIdx.x & 63;
    const size_t base = (size_t)r * DIM + lane * 2;
    float2 v = *(const float2*)(y + base);
    {
        float2 a = *(const float2*)(res + base);
        v.x += a.x; v.y += a.y;
    }
    if (res2) {
        float2 a = *(const float2*)(res2 + base);
        v.x += a.x; v.y += a.y;
    }
    if (res3) {
        float2 a = *(const float2*)(res3 + base);
        float2 c = *(const float2*)(res4 + base);
        v.x += a.x + c.x; v.y += a.y + c.y;
    }
    float s = v.x + v.y;
#pragma unroll
    for (int off = 32; off; off >>= 1) s += __shfl_xor(s, off, 64);
    const float mean = s * (1.f / 128.f);
    const float dx = v.x - mean, dy = v.y - mean;
    float q = dx * dx + dy * dy;
#pragma unroll
    for (int off = 32; off; off >>= 1) q += __shfl_xor(q, off, 64);
    const float rst = rsqrtf(q * (1.f / 128.f) + 1e-5f);
    const float2 gg = *(const float2*)(g + lane * 2);
    const float2 bb = *(const float2*)(b + lane * 2);
    float2 ov;
    ov.x = dx * rst * gg.x + bb.x;
    ov.y = dy * rst * gg.y + bb.y;
    *(float2*)(y + base) = ov;
    ushort2 pk;
    pk.x = f2b(ov.x);
    pk.y = f2b(ov.y);
    *(ushort2*)(yb + base) = pk;
}

// parallel mean-pool: grid (genre, 17 segments of 40 rows)
__global__ __launch_bounds__(256) void pool_partial(
    const float* __restrict__ y, const int* __restrict__ cnt, float* __restrict__ pooled)
{
    __shared__ float sh[128];
    const int g = blockIdx.x, seg = blockIdx.y, t = threadIdx.x;
    const int c = t & 127, h = t >> 7;
    const int L = cnt[g];
    const int k0 = seg * 40, k1 = min(k0 + 40, L);
    float s = 0.f;
    for (int k = k0 + h; k < k1; k += 2) s += y[((size_t)g * L_MAX + k) * DIM + c];
    if (h) sh[c] = s;
    __syncthreads();
    if (!h) {
        float tot = s + sh[c];
        if (k0 < L) atomicAdd(&pooled[g * DIM + c], tot / (float)max(L, 1));
    }
}

__global__ void build_fin(const float* __restrict__ acc, const float* __restrict__ pooled,
                          const int* __restrict__ midx, const int* __restrict__ genre,
                          ushort* __restrict__ A2)
{
    const int i = blockIdx.x, t = threadIdx.x;
    float v = (t < 128) ? acc[(size_t)midx[i] * DIM + t]
                        : pooled[genre[i] * DIM + (t - 128)];
    A2[(size_t)i * 256 + t] = f2b(v);
}

__global__ void scatter_movies(const float* __restrict__ fused, const int* __restrict__ midx,
                               float* __restrict__ out)
{
    const int i = blockIdx.x, c = threadIdx.x;
    out[(size_t)midx[i] * DIM + c] = fused[(size_t)i * DIM + c];
}

extern "C" void kernel_launch(void* const* d_in, const int* in_sizes, int n_in,
                              void* d_out, int out_size, void* d_ws, size_t ws_size,
                              hipStream_t stream)
{
    const float* x      = (const float*)d_in[0];
    const int* e[3]     = { (const int*)d_in[1], (const int*)d_in[2], (const int*)d_in[3] };
    const int* midx     = (const int*)d_in[4];
    const int* genre    = (const int*)d_in[5];
    const float* gatW   = (const float*)d_in[6];
    const float* attS   = (const float*)d_in[7];
    const float* attD   = (const float*)d_in[8];
    const float* gatB   = (const float*)d_in[9];
    const float* decW   = (const float*)d_in[10];
    const float* decB   = (const float*)d_in[11];
    const float* qkvW   = (const float*)d_in[12];
    const float* qkvB   = (const float*)d_in[13];
    const float* outW   = (const float*)d_in[14];
    const float* outB   = (const float*)d_in[15];
    const float* ln1g   = (const float*)d_in[16];
    const float* ln1b   = (const float*)d_in[17];
    const float* ln2g   = (const float*)d_in[18];
    const float* ln2b   = (const float*)d_in[19];
    const float* fw1    = (const float*)d_in[20];
    const float* fb1    = (const float*)d_in[21];
    const float* fw2    = (const float*)d_in[22];
    const float* fb2    = (const float*)d_in[23];
    const float* fusW   = (const float*)d_in[24];
    const float* fusB   = (const float*)d_in[25];
    float* out = (float*)d_out;

    // ---- workspace layout ----
    float* ws  = (float*)d_ws;
    float* acc = out;                             // final node features live in d_out
    float* R   = ws + 6400000;
    // stage A (ws low region + R):
    ushort* xb   = (ushort*)(ws);                 // 6.4M shorts
    ushort* gatWb= (ushort*)(ws + 3200000);       // 49,152 shorts
    ushort* decWb= (ushort*)(ws + 3224576);       // 49,152 shorts
    float*  als3 = ws + 3249152;                  // 600,000
    float*  ald3 = ws + 3849152;                  // 600,000
    int*    off3 = (int*)(ws + 4449152);          // 150,000
    int*    deg3 = (int*)(ws + 4599152);          // 150,000
    ushort* hb3  = (ushort*)(R);                  // 3 x 6.4M shorts
    ushort* gbx3 = (ushort*)(R + 9600000);        // 3 x 6.4M shorts
    int*   bcur  = (int*)(R + 19200000);          // 4,704 (3*98 x 16-int lines)
    int*   ebuf  = (int*)(R + 19204736);          // 1,354,752
    int*   srcs3 = (int*)(R + 20559488);          // 1,505,280 -> ends R+22,064,768
    // stage B (aliases stage A's R region):
    float*  ybuf  = R;                            // 2,611,200
    float*  tmp   = R + 2611200;                  // 2,611,200
    ushort* ybx   = (ushort*)(R + 5222400);       // 2,611,200 shorts
    ushort* attnb = (ushort*)(R + 6528000);       // 2,611,200 shorts
    ushort* qkvb  = (ushort*)(R + 7833600);       // 5,222,400 shorts (Q,K stride 256)
    ushort* vtg   = (ushort*)(R + 10444800);      // 2,611,200 shorts (V^T [128][20400])
    ushort* finb  = (ushort*)(R + 11750400);      // 5,222,400 shorts
    float*  tmp2  = R + 14361600;                 // 2,611,200 (FFN partial q1)
    float*  tmp3  = R + 16972800;                 // 2,611,200 (FFN partial q2)
    float*  tmp4  = R + 19584000;                 // 2,611,200 (FFN partial q3)
    float*  pooled= R + 22195200;                 // 3,840
    int*    cntb  = (int*)(R + 22199040);         // 32
    int*    posb  = cntb + 32;                    // 20,400
    ushort* qkvWb = (ushort*)(R + 22220000);      // 196,608 shorts
    ushort* outWb = (ushort*)(R + 22318304);      // 65,536 shorts
    ushort* fw1b  = (ushort*)(R + 22351072);      // 1,048,576 shorts
    ushort* fw2b  = (ushort*)(R + 22875360);      // 1,048,576 shorts
    ushort* fusWb = (ushort*)(R + 23399648);      // 32,768 shorts

    // ================= weight conversions (one launch) + x =================
    cvt_w<<<dim3(512, 7), 256, 0, stream>>>(
        gatW, decW, qkvW, outW, fw1, fw2, fusW,
        gatWb, decWb, qkvWb, outWb, fw1b, fw2b, fusWb);
    cvt32<<<(6400000 / 8 + 255) / 256, 256, 0, stream>>>(x, xb, 6400000 / 8);

    // ================= bucketed CSR build (all 3 hops) =================
    csr_initb<<<(3 * NBKT + 255) / 256, 256, 0, stream>>>(bcur);
    csr_route<<<dim3((N_EDGES + 4095) / 4096, 3), 256, 0, stream>>>(
        e[0], e[1], e[2], bcur, ebuf);
    csr_build<<<dim3(NBKT, 3), 256, 0, stream>>>(bcur, ebuf, off3, deg3, srcs3);

    // ================= Stage A: 3-hop GAT (hop-merged launches) =================
    gemm_lds<128, 0, 0, 1><<<dim3(391, 1, 3), 256, 0, stream>>>(
        xb, gatWb, nullptr, hb3, N_NODES, DIM, DIM, 1.f,
        (size_t)DIM * DIM, (size_t)N_NODES * DIM);
    gat_al<<<dim3((N_NODES * 4 + 255) / 256, 3), 256, 0, stream>>>(
        hb3, attS, attD, als3, ald3, N_NODES);
    gat_gather<<<dim3(N_NODES * 64 / 256, 3), 256, 0, stream>>>(
        off3, deg3, srcs3, hb3, als3, ald3, gatB, gbx3);
    dec3_gemm<<<391, 256, 0, stream>>>(gbx3, decWb, decB, acc, N_NODES);

    // ================= Stage B: genre transformer =================
    hipMemsetAsync(cntb, 0, 32 * 4, stream);
    calc_pos<<<(N_MOVIE + 255) / 256, 256, 0, stream>>>(genre, posb, cntb, N_MOVIE);
    build_y<<<N_MOVIE, 128, 0, stream>>>(acc, midx, genre, posb, ybuf, ybx);

    for (int l = 0; l < N_LAYERS; l++) {
        qkv_gemm<<<dim3(160, 3), 256, 0, stream>>>(
            ybx, qkvWb + (size_t)l * 384 * DIM, qkvB + l * 384, qkvb, vtg, NROWS);
        flash_attn<<<dim3(6, 4, 30), 256, 0, stream>>>(qkvb, vtg, cntb, attnb);
        proj_ln<<<(NROWS + 63) / 64, 256, 0, stream>>>(
            attnb, outWb + (size_t)l * DIM * DIM, outB + l * DIM,
            ybuf, ln1g + l * DIM, ln1b + l * DIM, ybx, NROWS);
        ffn_fused<<<dim3((NROWS + 127) / 128, 4), 256, 0, stream>>>(
            ybx, fw1b + (size_t)l * FF * DIM, fb1 + (size_t)l * FF,
            fw2b + (size_t)l * DIM * FF, fb2 + (size_t)l * DIM,
            tmp, tmp2, tmp3, tmp4, NROWS);
        ln_res<<<NROWS / 4, 256, 0, stream>>>(ybuf, tmp, tmp2, tmp3, tmp4,
                                              ln2g + l * DIM, ln2b + l * DIM, ybx);
    }

    hipMemsetAsync(pooled, 0, 3840 * 4, stream);
    pool_partial<<<dim3(N_GENRE, 17), 256, 0, stream>>>(ybuf, cntb, pooled);
    build_fin<<<N_MOVIE, 256, 0, stream>>>(acc, pooled, midx, genre, finb);
    gemm_lds<64, 1, 0, 0><<<dim3(319, 1, 1), 256, 0, stream>>>(
        finb, fusWb, fusB, tmp, NROWS, DIM, 256, 1.f, 0, 0);

    scatter_movies<<<N_MOVIE, 128, 0, stream>>>(tmp, midx, out);
}

// Round 11
// 814.670 us; speedup vs baseline: 1.0236x; 1.0013x over previous
//
#include <hip/hip_runtime.h>

#define N_NODES  50000
#define N_EDGES  400000
#define DIM      128
#define N_MOVIE  20400
#define N_GENRE  30
#define L_MAX    680
#define NROWS    (N_GENRE * L_MAX)   /* 20400 */
#define FF       2048
#define N_LAYERS 4

// bucketed CSR build
#define NBKT 98          /* bucket = dst >> 9 (512 nodes per bucket) */
#define NPB  512
#define ECAP 4608        /* edges per bucket capacity (mean 4096 + 8 sigma) */
#define SCAP 5120        /* CSR per bucket capacity (edges + selfs) */
#define EPGB (NBKT * ECAP)
#define SPGB (NBKT * SCAP)

typedef __attribute__((ext_vector_type(8))) short bf16x8;
typedef __attribute__((ext_vector_type(4))) float f32x4;

#define MFMA16 __builtin_amdgcn_mfma_f32_16x16x32_bf16

__device__ __forceinline__ float b2f(ushort u) {
    union { unsigned i; float f; } c; c.i = ((unsigned)u) << 16; return c.f;
}
__device__ __forceinline__ ushort f2b(float f) {
    union { float f; unsigned i; } c; c.f = f;
    unsigned u = c.i;
    u += 0x7FFFu + ((u >> 16) & 1u);   // RNE
    return (ushort)(u >> 16);
}
__device__ __forceinline__ bf16x8 load8s(const ushort* p) {
    return *(const bf16x8*)p;
}
__device__ __forceinline__ void async16(const ushort* g, ushort* l) {
    __builtin_amdgcn_global_load_lds(
        (const __attribute__((address_space(1))) void*)g,
        (__attribute__((address_space(3))) void*)l, 16, 0, 0);
}

__device__ __forceinline__ void cvt8(const float* s, ushort* d, int i) {
    const float4* q = (const float4*)(s + (size_t)i * 8);
    float4 a = q[0], b = q[1];
    bf16x8 r;
    r[0] = (short)f2b(a.x); r[1] = (short)f2b(a.y);
    r[2] = (short)f2b(a.z); r[3] = (short)f2b(a.w);
    r[4] = (short)f2b(b.x); r[5] = (short)f2b(b.y);
    r[6] = (short)f2b(b.z); r[7] = (short)f2b(b.w);
    *(bf16x8*)(d + (size_t)i * 8) = r;
}

// fp32 -> bf16, 8 elems/thread
__global__ void cvt32(const float* __restrict__ s, ushort* __restrict__ d, int n8)
{
    int i = blockIdx.x * blockDim.x + threadIdx.x;
    if (i < n8) cvt8(s, d, i);
}

// all 7 weight tensors in one launch (blockIdx.y selects tensor)
__global__ void cvt_w(const float* gatW, const float* decW, const float* qkvW,
                      const float* outW, const float* fw1, const float* fw2,
                      const float* fusW,
                      ushort* gatWb, ushort* decWb, ushort* qkvWb,
                      ushort* outWb, ushort* fw1b, ushort* fw2b, ushort* fusWb)
{
    const float* s; ushort* d; int n8;
    switch (blockIdx.y) {
        case 0: s = gatW; d = gatWb; n8 = 49152 / 8; break;
        case 1: s = decW; d = decWb; n8 = 49152 / 8; break;
        case 2: s = qkvW; d = qkvWb; n8 = 196608 / 8; break;
        case 3: s = outW; d = outWb; n8 = 65536 / 8; break;
        case 4: s = fw1;  d = fw1b;  n8 = 1048576 / 8; break;
        case 5: s = fw2;  d = fw2b;  n8 = 1048576 / 8; break;
        default: s = fusW; d = fusWb; n8 = 32768 / 8; break;
    }
    int i = blockIdx.x * 256 + threadIdx.x;
    if (i < n8) cvt8(s, d, i);
}

// ============ LDS-staged GEMM v2: full K=128 panel per stage ============
// C[M,N] = epi(A @ W^T + bias). K multiple of 128. XOR segment swizzle both-sides.
// blockIdx.z = slice index: W += z*wstride, OBF1 out += z*cstride.
// OBF: 0 = f32 out, 1 = bf16 out (LDS-staged coalesced write, BM=128 only).
template<int BM, int ACT, int EPI, int OBF>
__global__ __launch_bounds__(256) void gemm_lds(
    const ushort* __restrict__ A, const ushort* __restrict__ W_,
    const float* __restrict__ bias, void* __restrict__ Cv,
    int M, int N, int K, float scale, size_t wstride, size_t cstride)
{
    __shared__ ushort smem[BM * 128 + 128 * 128];
    ushort* As = smem;
    ushort* Ws = smem + BM * 128;
    const int tid  = threadIdx.x;
    const int wave = tid >> 6, lane = tid & 63;
    const int quad = lane >> 4, l16 = lane & 15;
    const int m0 = blockIdx.x * BM;
    const int n0 = blockIdx.y * 128;
    const int hop = blockIdx.z;
    const ushort* W = W_ + (size_t)hop * wstride;

    constexpr int MT = BM / 32;
    const int mbase = (wave & 1) * (BM / 2);
    const int nbase = (wave >> 1) * 64;

    f32x4 acc[MT][4] = {};
    for (int k0 = 0; k0 < K; k0 += 128) {
        if (k0) __syncthreads();
#pragma unroll
        for (int i = 0; i < BM / 16; i++) {
            int seg = i * 256 + tid;
            int r = seg >> 4, s = seg & 15;
            int rg = min(m0 + r, M - 1);
            async16(A + (size_t)rg * K + k0 + ((s ^ (r & 15)) * 8),
                    As + r * 128 + s * 8);
        }
#pragma unroll
        for (int i = 0; i < 8; i++) {
            int seg = i * 256 + tid;
            int r = seg >> 4, s = seg & 15;
            async16(W + (size_t)(n0 + r) * K + k0 + ((s ^ (r & 15)) * 8),
                    Ws + r * 128 + s * 8);
        }
        __syncthreads();

#pragma unroll
        for (int kk = 0; kk < 4; kk++) {
            bf16x8 a[MT], b[4];
#pragma unroll
            for (int mt = 0; mt < MT; mt++)
                a[mt] = load8s(As + (mbase + mt * 16 + l16) * 128 +
                               (((kk * 4 + quad) ^ l16) * 8));
#pragma unroll
            for (int nt = 0; nt < 4; nt++)
                b[nt] = load8s(Ws + (nbase + nt * 16 + l16) * 128 +
                               (((kk * 4 + quad) ^ l16) * 8));
#pragma unroll
            for (int mt = 0; mt < MT; mt++)
#pragma unroll
                for (int nt = 0; nt < 4; nt++)
                    acc[mt][nt] = MFMA16(a[mt], b[nt], acc[mt][nt], 0, 0, 0);
        }
    }

    if constexpr (OBF == 1) {
        static_assert(BM == 128, "OBF=1 staged epilogue assumes BM=128");
        ushort* Cs = smem;
        __syncthreads();
#pragma unroll
        for (int p = 0; p < 2; p++) {
            if ((wave & 1) == p) {
#pragma unroll
                for (int nt = 0; nt < 4; nt++) {
                    const int col = nbase + nt * 16 + l16;
                    const float bv = bias ? bias[n0 + col] : 0.f;
#pragma unroll
                    for (int mt = 0; mt < MT; mt++) {
                        const int rl = mt * 16 + quad * 4;
#pragma unroll
                        for (int r = 0; r < 4; r++) {
                            float v = acc[mt][nt][r] + bv;
                            if (ACT == 1) v = (v >= 0.f) ? v : 0.01f * v;
                            if (ACT == 2) v = fmaxf(v, 0.f);
                            Cs[(rl + r) * 128 + col] = f2b(v);
                        }
                    }
                }
            }
            __syncthreads();
            const int row = tid >> 2, cb = (tid & 3) * 32;   // 32 shorts = 64B
            const int grow = m0 + p * 64 + row;
            if (grow < M) {
                const ushort* s = Cs + row * 128 + cb;
                ushort* dp = (ushort*)Cv + (size_t)hop * cstride +
                             (size_t)grow * N + n0 + cb;
                *(int4*)(dp)      = *(const int4*)(s);
                *(int4*)(dp + 8)  = *(const int4*)(s + 8);
                *(int4*)(dp + 16) = *(const int4*)(s + 16);
                *(int4*)(dp + 24) = *(const int4*)(s + 24);
            }
            __syncthreads();
        }
    } else {
#pragma unroll
        for (int nt = 0; nt < 4; nt++) {
            const int col = n0 + nbase + nt * 16 + l16;
            const float bv = bias ? bias[col] : 0.f;
#pragma unroll
            for (int mt = 0; mt < MT; mt++) {
#pragma unroll
                for (int r = 0; r < 4; r++) {
                    const int row = m0 + mbase + mt * 16 + quad * 4 + r;
                    if (row < M) {
                        float v = acc[mt][nt][r] + bv;
                        if (ACT == 1) v = (v >= 0.f) ? v : 0.01f * v;
                        if (ACT == 2) v = fmaxf(v, 0.f);
                        const size_t idx = (size_t)row * N + col;
                        if (EPI == 1) ((float*)Cv)[idx] += scale * v;
                        else          ((float*)Cv)[idx] = v;
                    }
                }
            }
        }
    }
}

// ====== hop GEMM with fused attention-logit epilogue ======
// h = x @ gatW_hop^T (bf16 out) AND als/ald[n][head] = dot(h[n], a{src,dst}[head]).
// Wave owns 64 cols = 2 complete heads: head = (wave>>1)*2 + (nt>>1).
__global__ __launch_bounds__(256) void hop_gemm(
    const ushort* __restrict__ A, const ushort* __restrict__ W_,
    const float* __restrict__ asrc, const float* __restrict__ adst,
    ushort* __restrict__ hb3, float* __restrict__ als3, float* __restrict__ ald3,
    int M)
{
    __shared__ ushort smem[2 * 128 * 128];   // 64 KB
    ushort* As = smem;
    ushort* Ws = smem + 128 * 128;
    const int tid  = threadIdx.x;
    const int wave = tid >> 6, lane = tid & 63;
    const int quad = lane >> 4, l16 = lane & 15;
    const int m0 = blockIdx.x * 128;
    const int hop = blockIdx.z;
    const ushort* W = W_ + (size_t)hop * 128 * 128;
    const int mbase = (wave & 1) * 64;
    const int nbase = (wave >> 1) * 64;

    f32x4 acc[4][4] = {};
#pragma unroll
    for (int i = 0; i < 8; i++) {
        int seg = i * 256 + tid;
        int r = seg >> 4, s = seg & 15;
        int rg = min(m0 + r, M - 1);
        async16(A + (size_t)rg * 128 + ((s ^ (r & 15)) * 8), As + r * 128 + s * 8);
    }
#pragma unroll
    for (int i = 0; i < 8; i++) {
        int seg = i * 256 + tid;
        int r = seg >> 4, s = seg & 15;
        async16(W + (size_t)r * 128 + ((s ^ (r & 15)) * 8), Ws + r * 128 + s * 8);
    }
    __syncthreads();
#pragma unroll
    for (int kk = 0; kk < 4; kk++) {
        bf16x8 a[4], b[4];
#pragma unroll
        for (int mt = 0; mt < 4; mt++)
            a[mt] = load8s(As + (mbase + mt * 16 + l16) * 128 +
                           (((kk * 4 + quad) ^ l16) * 8));
#pragma unroll
        for (int nt = 0; nt < 4; nt++)
            b[nt] = load8s(Ws + (nbase + nt * 16 + l16) * 128 +
                           (((kk * 4 + quad) ^ l16) * 8));
#pragma unroll
        for (int mt = 0; mt < 4; mt++)
#pragma unroll
            for (int nt = 0; nt < 4; nt++)
                acc[mt][nt] = MFMA16(a[mt], b[nt], acc[mt][nt], 0, 0, 0);
    }

    // ---- fused al: per-thread partials over this wave's 2 heads ----
    {
        float sa[4][4][2] = {}, da[4][4][2] = {};
#pragma unroll
        for (int nt = 0; nt < 4; nt++) {
            const int col = nbase + nt * 16 + l16;
            const int hl = nt >> 1;
            const float as_ = asrc[hop * DIM + col];
            const float ad_ = adst[hop * DIM + col];
#pragma unroll
            for (int mt = 0; mt < 4; mt++)
#pragma unroll
                for (int r = 0; r < 4; r++) {
                    sa[mt][r][hl] += acc[mt][nt][r] * as_;
                    da[mt][r][hl] += acc[mt][nt][r] * ad_;
                }
        }
#pragma unroll
        for (int mt = 0; mt < 4; mt++)
#pragma unroll
            for (int r = 0; r < 4; r++)
#pragma unroll
                for (int hl = 0; hl < 2; hl++) {
#pragma unroll
                    for (int off = 1; off <= 8; off <<= 1) {
                        sa[mt][r][hl] += __shfl_xor(sa[mt][r][hl], off, 64);
                        da[mt][r][hl] += __shfl_xor(da[mt][r][hl], off, 64);
                    }
                }
        if (l16 == 0) {
            const int hbase = (wave >> 1) * 2;
#pragma unroll
            for (int mt = 0; mt < 4; mt++)
#pragma unroll
                for (int r = 0; r < 4; r++) {
                    const int gm = m0 + mbase + mt * 16 + quad * 4 + r;
                    if (gm < M) {
#pragma unroll
                        for (int hl = 0; hl < 2; hl++) {
                            const size_t idx = (size_t)hop * M * 4 +
                                               (size_t)gm * 4 + hbase + hl;
                            als3[idx] = sa[mt][r][hl];
                            ald3[idx] = da[mt][r][hl];
                        }
                    }
                }
        }
    }

    // ---- bf16 h write via LDS-staged coalesced epilogue ----
    ushort* Cs = smem;
    __syncthreads();
#pragma unroll
    for (int p = 0; p < 2; p++) {
        if ((wave & 1) == p) {
#pragma unroll
            for (int nt = 0; nt < 4; nt++) {
                const int col = nbase + nt * 16 + l16;
#pragma unroll
                for (int mt = 0; mt < 4; mt++) {
                    const int rl = mt * 16 + quad * 4;
#pragma unroll
                    for (int r = 0; r < 4; r++)
                        Cs[(rl + r) * 128 + col] = f2b(acc[mt][nt][r]);
                }
            }
        }
        __syncthreads();
        const int row = tid >> 2, cb = (tid & 3) * 32;
        const int grow = m0 + p * 64 + row;
        if (grow < M) {
            const ushort* s = Cs + row * 128 + cb;
            ushort* dp = hb3 + (size_t)hop * M * DIM + (size_t)grow * 128 + cb;
            *(int4*)(dp)      = *(const int4*)(s);
            *(int4*)(dp + 8)  = *(const int4*)(s + 8);
            *(int4*)(dp + 16) = *(const int4*)(s + 16);
            *(int4*)(dp + 24) = *(const int4*)(s + 24);
        }
        __syncthreads();
    }
}

// ====== merged 3-hop decoder GEMM: acc = sum_k decay_k*leaky(gbx_k@decW_k^T+b_k) ======
__global__ __launch_bounds__(256) void dec3_gemm(
    const ushort* __restrict__ gbx3, const ushort* __restrict__ decWb,
    const float* __restrict__ decB, float* __restrict__ outp, int M)
{
    __shared__ ushort smem[2 * 128 * 128];   // 64 KB
    ushort* As = smem;
    ushort* Ws = smem + 128 * 128;
    const int tid  = threadIdx.x;
    const int wave = tid >> 6, lane = tid & 63;
    const int quad = lane >> 4, l16 = lane & 15;
    const int m0 = blockIdx.x * 128;
    const int mbase = (wave & 1) * 64;
    const int nbase = (wave >> 1) * 64;
    const float decay[3] = { 1.0f, 0.90483741803595952f, 0.81873075307798182f };

    float fac[4][4][4] = {};
    for (int hop = 0; hop < 3; hop++) {
        if (hop) __syncthreads();
        const ushort* A = gbx3 + (size_t)hop * M * DIM;
        const ushort* W = decWb + hop * DIM * DIM;
#pragma unroll
        for (int i = 0; i < 8; i++) {
            int seg = i * 256 + tid;
            int r = seg >> 4, s = seg & 15;
            int rg = min(m0 + r, M - 1);
            async16(A + (size_t)rg * 128 + ((s ^ (r & 15)) * 8), As + r * 128 + s * 8);
        }
#pragma unroll
        for (int i = 0; i < 8; i++) {
            int seg = i * 256 + tid;
            int r = seg >> 4, s = seg & 15;
            async16(W + (size_t)r * 128 + ((s ^ (r & 15)) * 8), Ws + r * 128 + s * 8);
        }
        __syncthreads();
        f32x4 acc[4][4] = {};
#pragma unroll
        for (int kk = 0; kk < 4; kk++) {
            bf16x8 a[4], b[4];
#pragma unroll
            for (int mt = 0; mt < 4; mt++)
                a[mt] = load8s(As + (mbase + mt * 16 + l16) * 128 +
                               (((kk * 4 + quad) ^ l16) * 8));
#pragma unroll
            for (int nt = 0; nt < 4; nt++)
                b[nt] = load8s(Ws + (nbase + nt * 16 + l16) * 128 +
                               (((kk * 4 + quad) ^ l16) * 8));
#pragma unroll
            for (int mt = 0; mt < 4; mt++)
#pragma unroll
                for (int nt = 0; nt < 4; nt++)
                    acc[mt][nt] = MFMA16(a[mt], b[nt], acc[mt][nt], 0, 0, 0);
        }
        const float dk = decay[hop];
#pragma unroll
        for (int nt = 0; nt < 4; nt++) {
            const int col = nbase + nt * 16 + l16;
            const float bv = decB[hop * DIM + col];
#pragma unroll
            for (int mt = 0; mt < 4; mt++)
#pragma unroll
                for (int r = 0; r < 4; r++) {
                    float v = acc[mt][nt][r] + bv;
                    v = (v >= 0.f) ? v : 0.01f * v;
                    fac[mt][nt][r] += dk * v;
                }
        }
    }
#pragma unroll
    for (int nt = 0; nt < 4; nt++) {
        const int col = nbase + nt * 16 + l16;
#pragma unroll
        for (int mt = 0; mt < 4; mt++)
#pragma unroll
            for (int r = 0; r < 4; r++) {
                const int row = m0 + mbase + mt * 16 + quad * 4 + r;
                if (row < M) outp[(size_t)row * 128 + col] = fac[mt][nt][r];
            }
    }
}

// ====== fused out-proj + residual + LayerNorm (post-LN attn branch) ======
__global__ __launch_bounds__(256) void proj_ln(
    const ushort* __restrict__ A, const ushort* __restrict__ W,
    const float* __restrict__ bias, float* __restrict__ y,
    const float* __restrict__ g, const float* __restrict__ b,
    ushort* __restrict__ yb, int M)
{
    __shared__ ushort smem[64 * 128 + 128 * 128];   // 48 KB
    __shared__ float lnsum[64][2], lnsq[64][2];
    ushort* As = smem;
    ushort* Ws = smem + 64 * 128;
    const int tid  = threadIdx.x;
    const int wave = tid >> 6, lane = tid & 63;
    const int quad = lane >> 4, l16 = lane & 15;
    const int m0 = blockIdx.x * 64;
    const int mbase = (wave & 1) * 32;
    const int nbase = (wave >> 1) * 64;
    const int half = wave >> 1;

#pragma unroll
    for (int i = 0; i < 4; i++) {
        int seg = i * 256 + tid;
        int r = seg >> 4, s = seg & 15;
        int rg = min(m0 + r, M - 1);
        async16(A + (size_t)rg * 128 + ((s ^ (r & 15)) * 8), As + r * 128 + s * 8);
    }
#pragma unroll
    for (int i = 0; i < 8; i++) {
        int seg = i * 256 + tid;
        int r = seg >> 4, s = seg & 15;
        async16(W + (size_t)r * 128 + ((s ^ (r & 15)) * 8), Ws + r * 128 + s * 8);
    }
    __syncthreads();

    f32x4 acc[2][4] = {};
#pragma unroll
    for (int kk = 0; kk < 4; kk++) {
        bf16x8 a[2], bfr[4];
#pragma unroll
        for (int mt = 0; mt < 2; mt++)
            a[mt] = load8s(As + (mbase + mt * 16 + l16) * 128 +
                           (((kk * 4 + quad) ^ l16) * 8));
#pragma unroll
        for (int nt = 0; nt < 4; nt++)
            bfr[nt] = load8s(Ws + (nbase + nt * 16 + l16) * 128 +
                             (((kk * 4 + quad) ^ l16) * 8));
#pragma unroll
        for (int mt = 0; mt < 2; mt++)
#pragma unroll
            for (int nt = 0; nt < 4; nt++)
                acc[mt][nt] = MFMA16(a[mt], bfr[nt], acc[mt][nt], 0, 0, 0);
    }

    // residual add + row partial sums
    float vv[2][4][4];
    float rs[2][4] = {};
#pragma unroll
    for (int mt = 0; mt < 2; mt++)
#pragma unroll
        for (int nt = 0; nt < 4; nt++) {
            const int col = nbase + nt * 16 + l16;
            const float bv = bias[col];
#pragma unroll
            for (int rr = 0; rr < 4; rr++) {
                const int row = m0 + mbase + mt * 16 + quad * 4 + rr;
                float v = acc[mt][nt][rr] + bv;
                if (row < M) v += y[(size_t)row * 128 + col];
                vv[mt][nt][rr] = v;
                rs[mt][rr] += v;
            }
        }
#pragma unroll
    for (int mt = 0; mt < 2; mt++)
#pragma unroll
        for (int rr = 0; rr < 4; rr++) {
#pragma unroll
            for (int off = 1; off <= 8; off <<= 1)
                rs[mt][rr] += __shfl_xor(rs[mt][rr], off, 64);
            if (l16 == 0)
                lnsum[mbase + mt * 16 + quad * 4 + rr][half] = rs[mt][rr];
        }
    __syncthreads();

    float mean[2][4];
#pragma unroll
    for (int mt = 0; mt < 2; mt++)
#pragma unroll
        for (int rr = 0; rr < 4; rr++) {
            const int rl = mbase + mt * 16 + quad * 4 + rr;
            mean[mt][rr] = (lnsum[rl][0] + lnsum[rl][1]) * (1.f / 128.f);
            float q = 0.f;
#pragma unroll
            for (int nt = 0; nt < 4; nt++) {
                float d = vv[mt][nt][rr] - mean[mt][rr];
                q += d * d;
            }
#pragma unroll
            for (int off = 1; off <= 8; off <<= 1)
                q += __shfl_xor(q, off, 64);
            if (l16 == 0) lnsq[rl][half] = q;
        }
    __syncthreads();

#pragma unroll
    for (int mt = 0; mt < 2; mt++)
#pragma unroll
        for (int rr = 0; rr < 4; rr++) {
            const int rl = mbase + mt * 16 + quad * 4 + rr;
            const int row = m0 + rl;
            const float rstd = rsqrtf((lnsq[rl][0] + lnsq[rl][1]) * (1.f / 128.f) + 1e-5f);
            if (row < M) {
#pragma unroll
                for (int nt = 0; nt < 4; nt++) {
                    const int col = nbase + nt * 16 + l16;
                    float o = (vv[mt][nt][rr] - mean[mt][rr]) * rstd * g[col] + b[col];
                    y[(size_t)row * 128 + col] = o;
                    yb[(size_t)row * 128 + col] = f2b(o);
                }
            }
        }
}

// ====== merged QKV + V^T GEMM: grid (160, 3) ======
__global__ __launch_bounds__(256) void qkv_gemm(
    const ushort* __restrict__ A, const ushort* __restrict__ W0,
    const float* __restrict__ bias0, ushort* __restrict__ qkv,
    ushort* __restrict__ vt, int M)
{
    __shared__ ushort smem[2 * 128 * 128];
    ushort* As = smem;
    ushort* Ws = smem + 128 * 128;
    const int tid  = threadIdx.x;
    const int wave = tid >> 6, lane = tid & 63;
    const int quad = lane >> 4, l16 = lane & 15;
    const int m0 = blockIdx.x * 128;
    const int sel = blockIdx.y;
    const ushort* W = W0 + (size_t)sel * 128 * 128;
    const int mbase = (wave & 1) * 64;
    const int nbase = (wave >> 1) * 64;

    f32x4 acc[4][4] = {};
#pragma unroll
    for (int i = 0; i < 8; i++) {
        int seg = i * 256 + tid;
        int r = seg >> 4, s = seg & 15;
        int rg = min(m0 + r, M - 1);
        async16(A + (size_t)rg * 128 + ((s ^ (r & 15)) * 8), As + r * 128 + s * 8);
    }
#pragma unroll
    for (int i = 0; i < 8; i++) {
        int seg = i * 256 + tid;
        int r = seg >> 4, s = seg & 15;
        async16(W + (size_t)r * 128 + ((s ^ (r & 15)) * 8), Ws + r * 128 + s * 8);
    }
    __syncthreads();
#pragma unroll
    for (int kk = 0; kk < 4; kk++) {
        bf16x8 a[4], b[4];
#pragma unroll
        for (int mt = 0; mt < 4; mt++)
            a[mt] = load8s(As + (mbase + mt * 16 + l16) * 128 +
                           (((kk * 4 + quad) ^ l16) * 8));
#pragma unroll
        for (int nt = 0; nt < 4; nt++)
            b[nt] = load8s(Ws + (nbase + nt * 16 + l16) * 128 +
                           (((kk * 4 + quad) ^ l16) * 8));
#pragma unroll
        for (int mt = 0; mt < 4; mt++)
#pragma unroll
            for (int nt = 0; nt < 4; nt++)
                acc[mt][nt] = MFMA16(a[mt], b[nt], acc[mt][nt], 0, 0, 0);
    }

    if (sel < 2) {
        ushort* Cs = smem;
        __syncthreads();
#pragma unroll
        for (int p = 0; p < 2; p++) {
            if ((wave & 1) == p) {
#pragma unroll
                for (int nt = 0; nt < 4; nt++) {
                    const int col = nbase + nt * 16 + l16;
                    const float bv = bias0[sel * 128 + col];
#pragma unroll
                    for (int mt = 0; mt < 4; mt++) {
                        const int rl = mt * 16 + quad * 4;
#pragma unroll
                        for (int r = 0; r < 4; r++)
                            Cs[(rl + r) * 128 + col] = f2b(acc[mt][nt][r] + bv);
                    }
                }
            }
            __syncthreads();
            const int row = tid >> 2, cb = (tid & 3) * 32;
            const int grow = m0 + p * 64 + row;
            if (grow < M) {
                const ushort* s = Cs + row * 128 + cb;
                ushort* dp = qkv + (size_t)grow * 256 + sel * 128 + cb;
                *(int4*)(dp)      = *(const int4*)(s);
                *(int4*)(dp + 8)  = *(const int4*)(s + 8);
                *(int4*)(dp + 16) = *(const int4*)(s + 16);
                *(int4*)(dp + 24) = *(const int4*)(s + 24);
            }
            __syncthreads();
        }
    } else {
#pragma unroll
        for (int nt = 0; nt < 4; nt++) {
            const int col = nbase + nt * 16 + l16;
            const float bv = bias0[256 + col];
#pragma unroll
            for (int mt = 0; mt < 4; mt++) {
                const int row0 = m0 + mbase + mt * 16 + quad * 4;
                if (row0 < M) {
                    ushort4 pk;
                    pk.x = f2b(acc[mt][nt][0] + bv);
                    pk.y = f2b(acc[mt][nt][1] + bv);
                    pk.z = f2b(acc[mt][nt][2] + bv);
                    pk.w = f2b(acc[mt][nt][3] + bv);
                    *(ushort4*)(vt + (size_t)col * M + row0) = pk;
                }
            }
        }
    }
}

// ====== Fused FFN (R4-proven): LDS-staged weights, 4 FF-quarters ======
__global__ __launch_bounds__(256, 2) void ffn_fused(
    const ushort* __restrict__ y, const ushort* __restrict__ w1,
    const float* __restrict__ b1, const ushort* __restrict__ w2,
    const float* __restrict__ b2,
    float* __restrict__ o0, float* __restrict__ o1,
    float* __restrict__ o2, float* __restrict__ o3, int M)
{
    __shared__ ushort f1s[2][32 * 128];   // 2x8 KB
    __shared__ ushort f2s[2][128 * 32];   // 2x8 KB
    __shared__ ushort mids[4][32 * 40];   // 10 KB wave-private
    const int tid  = threadIdx.x;
    const int wave = tid >> 6, lane = tid & 63;
    const int quad = lane >> 4, l16 = lane & 15;
    const int m0 = blockIdx.x * 128;
    const int fh = blockIdx.y;
    const int fbase = fh * (FF / 4);
    float* o = (fh == 0) ? o0 : (fh == 1) ? o1 : (fh == 2) ? o2 : o3;

    const int sw1 = ((tid & 15) ^ (tid >> 4)) * 8;
    const int sw2 = ((tid & 3) ^ ((tid >> 3) & 3)) * 8;

    const int wrow = m0 + wave * 32;
    bf16x8 yf[2][4];
#pragma unroll
    for (int mt = 0; mt < 2; mt++) {
        const int mr = min(wrow + mt * 16 + l16, M - 1);
#pragma unroll
        for (int ks = 0; ks < 4; ks++)
            yf[mt][ks] = load8s(y + (size_t)mr * 128 + ks * 32 + quad * 8);
    }

#pragma unroll
    for (int i = 0; i < 2; i++) {
        int row = i * 16 + (tid >> 4);
        async16(w1 + (size_t)(fbase + row) * 128 + sw1,
                f1s[0] + row * 128 + (tid & 15) * 8);
    }
#pragma unroll
    for (int i = 0; i < 2; i++) {
        int row = i * 64 + (tid >> 2);
        async16(w2 + (size_t)row * FF + fbase + sw2,
                f2s[0] + row * 32 + (tid & 3) * 8);
    }

    f32x4 oacc[2][8] = {};
    ushort* midw = mids[wave];
    int cur = 0;
    __syncthreads();

    for (int fo = 0; fo < FF / 4; fo += 32) {
        if (fo + 32 < FF / 4) {
            const int fn = fbase + fo + 32;
#pragma unroll
            for (int i = 0; i < 2; i++) {
                int row = i * 16 + (tid >> 4);
                async16(w1 + (size_t)(fn + row) * 128 + sw1,
                        f1s[cur ^ 1] + row * 128 + (tid & 15) * 8);
            }
#pragma unroll
            for (int i = 0; i < 2; i++) {
                int row = i * 64 + (tid >> 2);
                async16(w2 + (size_t)row * FF + fn + sw2,
                        f2s[cur ^ 1] + row * 32 + (tid & 3) * 8);
            }
        }
        const ushort* F1 = f1s[cur];
        const ushort* F2 = f2s[cur];

        f32x4 midacc[2][2] = {};
#pragma unroll
        for (int ks = 0; ks < 4; ks++) {
            const int csA = (((ks * 4 + quad) ^ l16) & 15) * 8;
#pragma unroll
            for (int ft = 0; ft < 2; ft++) {
                bf16x8 wf = load8s(F1 + (ft * 16 + l16) * 128 + csA);
                midacc[0][ft] = MFMA16(wf, yf[0][ks], midacc[0][ft], 0, 0, 0);
                midacc[1][ft] = MFMA16(wf, yf[1][ks], midacc[1][ft], 0, 0, 0);
            }
        }
#pragma unroll
        for (int mt = 0; mt < 2; mt++)
#pragma unroll
            for (int ft = 0; ft < 2; ft++) {
                const float4 bb = *(const float4*)(b1 + fbase + fo + ft * 16 + quad * 4);
                ushort4 pk;
                pk.x = f2b(fmaxf(midacc[mt][ft][0] + bb.x, 0.f));
                pk.y = f2b(fmaxf(midacc[mt][ft][1] + bb.y, 0.f));
                pk.z = f2b(fmaxf(midacc[mt][ft][2] + bb.z, 0.f));
                pk.w = f2b(fmaxf(midacc[mt][ft][3] + bb.w, 0.f));
                *(ushort4*)(midw + (mt * 16 + l16) * 40 + ft * 16 + quad * 4) = pk;
            }
        bf16x8 mf0 = load8s(midw + (size_t)l16 * 40 + quad * 8);
        bf16x8 mf1 = load8s(midw + (size_t)(16 + l16) * 40 + quad * 8);
        const int gB = (quad ^ ((l16 >> 1) & 3)) * 8;
#pragma unroll
        for (int dt = 0; dt < 8; dt++) {
            bf16x8 wf = load8s(F2 + (dt * 16 + l16) * 32 + gB);
            oacc[0][dt] = MFMA16(wf, mf0, oacc[0][dt], 0, 0, 0);
            oacc[1][dt] = MFMA16(wf, mf1, oacc[1][dt], 0, 0, 0);
        }
        __syncthreads();
        cur ^= 1;
    }

#pragma unroll
    for (int mt = 0; mt < 2; mt++) {
        const int m = wrow + mt * 16 + l16;
        if (m < M) {
            float* op = o + (size_t)m * 128 + quad * 4;
#pragma unroll
            for (int dt = 0; dt < 8; dt++) {
                float4 v;
                if (fh == 0) {
                    const float4 bv = *(const float4*)(b2 + dt * 16 + quad * 4);
                    v.x = oacc[mt][dt][0] + bv.x;
                    v.y = oacc[mt][dt][1] + bv.y;
                    v.z = oacc[mt][dt][2] + bv.z;
                    v.w = oacc[mt][dt][3] + bv.w;
                } else {
                    v.x = oacc[mt][dt][0];
                    v.y = oacc[mt][dt][1];
                    v.z = oacc[mt][dt][2];
                    v.w = oacc[mt][dt][3];
                }
                *(float4*)(op + dt * 16) = v;
            }
        }
    }
}

// ---------------- bucketed CSR build ----------------
__global__ void csr_initb(int* __restrict__ bcur)
{
    int i = blockIdx.x * 256 + threadIdx.x;
    if (i < 3 * NBKT) bcur[i * 16] = (i % NBKT) * ECAP;
}

__global__ __launch_bounds__(256) void csr_route(
    const int* __restrict__ e0, const int* __restrict__ e1, const int* __restrict__ e2,
    int* __restrict__ bcur, int* __restrict__ ebuf)
{
    __shared__ int hist[NBKT], base[NBKT], cur[NBKT];
    const int g = blockIdx.y, t = threadIdx.x;
    const int* e = (g == 0) ? e0 : (g == 1) ? e1 : e2;
    const int i0 = blockIdx.x * 4096;
    for (int j = t; j < NBKT; j += 256) { hist[j] = 0; cur[j] = 0; }
    __syncthreads();
    unsigned pk[16]; int bk[16];
#pragma unroll
    for (int j = 0; j < 16; j++) {
        int i = i0 + j * 256 + t;
        if (i < N_EDGES) {
            int s = e[i], d = e[N_EDGES + i];
            bk[j] = d >> 9;
            pk[j] = (unsigned)s | ((unsigned)(d & 511) << 16);
            atomicAdd(&hist[bk[j]], 1);
        } else bk[j] = -1;
    }
    __syncthreads();
    for (int j = t; j < NBKT; j += 256)
        if (hist[j]) base[j] = atomicAdd(&bcur[(g * NBKT + j) * 16], hist[j]);
    __syncthreads();
#pragma unroll
    for (int j = 0; j < 16; j++)
        if (bk[j] >= 0) {
            int p = base[bk[j]] + atomicAdd(&cur[bk[j]], 1);
            ebuf[(size_t)g * EPGB + p] = (int)pk[j];
        }
}

__global__ __launch_bounds__(256) void csr_build(
    const int* __restrict__ bcur, const int* __restrict__ ebuf,
    int* __restrict__ off, int* __restrict__ deg, int* __restrict__ srcs)
{
    __shared__ int hist[NPB];
    __shared__ int part[256];
    const int g = blockIdx.y, b = blockIdx.x, t = threadIdx.x;
    const int nb0 = b * NPB;
    const int nn = min(NPB, N_NODES - nb0);
    const int cnt = bcur[(g * NBKT + b) * 16] - b * ECAP;
    const int* eb = ebuf + (size_t)g * EPGB + b * ECAP;

    for (int j = t; j < NPB; j += 256) hist[j] = (j < nn) ? 1 : 0;   // self-loop
    __syncthreads();
    for (int i = t; i < cnt; i += 256)
        atomicAdd(&hist[(eb[i] >> 16) & 511], 1);
    __syncthreads();

    int a0 = hist[t * 2], a1 = hist[t * 2 + 1];
    int sum = a0 + a1;
    part[t] = sum;
    __syncthreads();
    for (int d = 1; d < 256; d <<= 1) {
        int x = (t >= d) ? part[t - d] : 0;
        __syncthreads();
        part[t] += x;
        __syncthreads();
    }
    const int excl = part[t] - sum;
    __syncthreads();
    const int sb = b * SCAP;
    hist[t * 2]     = excl;
    hist[t * 2 + 1] = excl + a0;
    if (t * 2 < nn) {
        off[(size_t)g * N_NODES + nb0 + t * 2] = sb + excl;
        deg[(size_t)g * N_NODES + nb0 + t * 2] = a0;
    }
    if (t * 2 + 1 < nn) {
        off[(size_t)g * N_NODES + nb0 + t * 2 + 1] = sb + excl + a0;
        deg[(size_t)g * N_NODES + nb0 + t * 2 + 1] = a1;
    }
    __syncthreads();

    int* sg = srcs + (size_t)g * SPGB + sb;
    for (int i = t; i < cnt; i += 256) {
        int v = eb[i];
        int p = atomicAdd(&hist[(v >> 16) & 511], 1);
        sg[p] = v & 0xFFFF;
    }
    for (int j = t; j < nn; j += 256) {
        int p = atomicAdd(&hist[j], 1);
        sg[p] = nb0 + j;
    }
}

// one wave per dst, 4 edge-groups x 16 lanes, 2 edges per group per iteration
// (j and j+4; next pair's srcs prefetched). All 3 hops (blockIdx.y = hop).
__global__ __launch_bounds__(256) void gat_gather(
    const int* __restrict__ off3, const int* __restrict__ deg3,
    const int* __restrict__ srcs3, const ushort* __restrict__ hb3,
    const float* __restrict__ als3, const float* __restrict__ ald3,
    const float* __restrict__ bias3, ushort* __restrict__ gbx3)
{
    int w = (blockIdx.x * 256 + threadIdx.x) >> 6;
    int lane = threadIdx.x & 63;
    if (w >= N_NODES) return;
    const int hop = blockIdx.y;
    const int* off = off3 + (size_t)hop * N_NODES;
    const int* deg = deg3 + (size_t)hop * N_NODES;
    const int* srcs = srcs3 + (size_t)hop * SPGB;
    const ushort* hb = hb3 + (size_t)hop * N_NODES * DIM;
    const float* als = als3 + (size_t)hop * N_NODES * 4;
    const float* ald = ald3 + (size_t)hop * N_NODES * 4;
    const float* bias = bias3 + hop * DIM;
    ushort* ob = gbx3 + (size_t)hop * N_NODES * DIM;

    const int grp  = lane >> 4;
    const int l16  = lane & 15;
    const int head = l16 >> 2;
    const float adv = ald[(size_t)w * 4 + head];
    const int jb = off[w], dg = deg[w];

    float acc[8] = {};
    float wsum = 0.f;

    int j = grp;
    int s0 = (j < dg)     ? srcs[jb + j]     : 0;
    int s1 = (j + 4 < dg) ? srcs[jb + j + 4] : 0;
    while (j < dg) {
        const int jn = j + 8;
        const int sn0 = (jn < dg)     ? srcs[jb + jn]     : 0;
        const int sn1 = (jn + 4 < dg) ? srcs[jb + jn + 4] : 0;
        const bool has1 = (j + 4 < dg);
        // issue both row loads before the VALU chain (independent latencies)
        bf16x8 hv0 = load8s(hb + (size_t)s0 * DIM + l16 * 8);
        bf16x8 hv1 = load8s(hb + (size_t)s1 * DIM + l16 * 8);
        float e0 = als[(size_t)s0 * 4 + head] + adv;
        e0 = (e0 >= 0.f) ? e0 : 0.2f * e0;
        float e1 = als[(size_t)s1 * 4 + head] + adv;
        e1 = (e1 >= 0.f) ? e1 : 0.2f * e1;
        const float w0 = __expf(e0);
        const float w1 = has1 ? __expf(e1) : 0.f;
        wsum += w0 + w1;
#pragma unroll
        for (int c = 0; c < 8; c++)
            acc[c] += w0 * b2f((ushort)hv0[c]) + w1 * b2f((ushort)hv1[c]);
        j = jn; s0 = sn0; s1 = sn1;
    }

    wsum += __shfl_xor(wsum, 16, 64);
    wsum += __shfl_xor(wsum, 32, 64);
#pragma unroll
    for (int c = 0; c < 8; c++) {
        acc[c] += __shfl_xor(acc[c], 16, 64);
        acc[c] += __shfl_xor(acc[c], 32, 64);
    }

    if (grp == 0) {
        const float inv = 1.f / wsum;
        bf16x8 r;
#pragma unroll
        for (int c = 0; c < 8; c++)
            r[c] = (short)f2b(acc[c] * inv + bias[l16 * 8 + c]);
        *(bf16x8*)(ob + (size_t)w * DIM + l16 * 8) = r;
    }
}

__global__ void calc_pos(const int* __restrict__ genre, int* __restrict__ pos,
                         int* __restrict__ cnt, int NM)
{
    int i = blockIdx.x * blockDim.x + threadIdx.x;
    if (i < NM) pos[i] = atomicAdd(&cnt[genre[i]], 1);
}

__global__ void build_y(const float* __restrict__ acc, const int* __restrict__ midx,
                        const int* __restrict__ genre, const int* __restrict__ pos,
                        float* __restrict__ y, ushort* __restrict__ yb)
{
    int i = blockIdx.x, c = threadIdx.x;
    int g = genre[i], p = pos[i];
    float v = acc[(size_t)midx[i] * DIM + c];
    size_t o = ((size_t)g * L_MAX + p) * DIM + c;
    y[o] = v; yb[o] = f2b(v);
}

// ======== barrier-free flash attention: V^T pre-transposed in global ========
#define SP 40    /* P row stride in shorts (80 B, 16B-aligned) */

__global__ __launch_bounds__(256) void flash_attn(
    const ushort* __restrict__ qk, const ushort* __restrict__ vtg,
    const int* __restrict__ cnt, ushort* __restrict__ o)
{
    __shared__ ushort Pb[4][32 * SP];     // 10240 B, wave-private tiles

    const int qt = blockIdx.x, hh = blockIdx.y, g = blockIdx.z;
    const int t = threadIdx.x, wave = t >> 6, lane = t & 63;
    const int quad = lane >> 4, l16 = lane & 15;
    const int L = cnt[g];
    const float scale = 0.17677669529663687f;   // 1/sqrt(32)
    const ushort* base = qk + (size_t)g * L_MAX * 256;
    const ushort* vb0 = vtg + (size_t)(hh * 32 + l16) * NROWS + g * L_MAX;
    const ushort* vb1 = vb0 + (size_t)16 * NROWS;

    const int q0 = qt * 128 + wave * 32;
    bf16x8 a0 = load8s(base + (size_t)min(q0 + l16,      L_MAX - 1) * 256 + hh * 32 + quad * 8);
    bf16x8 a1 = load8s(base + (size_t)min(q0 + 16 + l16, L_MAX - 1) * 256 + hh * 32 + quad * 8);

    f32x4 oacc[2][2] = {};        // [dhalf][qhalf], O^T layout
    float rsum[2] = {0.f, 0.f};
    ushort* P = Pb[wave];

    for (int kt = 0; kt < 704; kt += 32) {
        bf16x8 b0 = load8s(base + (size_t)min(kt + l16,      L_MAX - 1) * 256 + 128 + hh * 32 + quad * 8);
        bf16x8 b1 = load8s(base + (size_t)min(kt + 16 + l16, L_MAX - 1) * 256 + 128 + hh * 32 + quad * 8);
        f32x4 z = {};
        f32x4 st00 = MFMA16(b0, a0, z, 0, 0, 0);   // S^T[k][q]
        f32x4 st01 = MFMA16(b0, a1, z, 0, 0, 0);
        f32x4 st10 = MFMA16(b1, a0, z, 0, 0, 0);
        f32x4 st11 = MFMA16(b1, a1, z, 0, 0, 0);

        const int kc0 = kt + quad * 4, kc1 = kt + 16 + quad * 4;
#pragma unroll
        for (int qh = 0; qh < 2; qh++) {
            const f32x4 sA = qh ? st01 : st00;
            const f32x4 sB = qh ? st11 : st10;
            float w[8];
#pragma unroll
            for (int r = 0; r < 4; r++) {
                w[r]     = (kc0 + r < L) ? __expf(sA[r] * scale) : 0.f;
                w[4 + r] = (kc1 + r < L) ? __expf(sB[r] * scale) : 0.f;
                rsum[qh] += w[r] + w[4 + r];
            }
            ushort4 pk0, pk1;
            pk0.x = f2b(w[0]); pk0.y = f2b(w[1]); pk0.z = f2b(w[2]); pk0.w = f2b(w[3]);
            pk1.x = f2b(w[4]); pk1.y = f2b(w[5]); pk1.z = f2b(w[6]); pk1.w = f2b(w[7]);
            *(ushort4*)(P + (qh * 16 + l16) * SP + quad * 4)      = pk0;
            *(ushort4*)(P + (qh * 16 + l16) * SP + 16 + quad * 4) = pk1;
        }
        bf16x8 p0 = load8s(P + (size_t)l16 * SP + quad * 8);
        bf16x8 p1 = load8s(P + (size_t)(16 + l16) * SP + quad * 8);
        bf16x8 v0 = load8s(vb0 + kt + quad * 8);
        bf16x8 v1 = load8s(vb1 + kt + quad * 8);
        oacc[0][0] = MFMA16(v0, p0, oacc[0][0], 0, 0, 0);
        oacc[0][1] = MFMA16(v0, p1, oacc[0][1], 0, 0, 0);
        oacc[1][0] = MFMA16(v1, p0, oacc[1][0], 0, 0, 0);
        oacc[1][1] = MFMA16(v1, p1, oacc[1][1], 0, 0, 0);
    }

#pragma unroll
    for (int qh = 0; qh < 2; qh++) {
        float s = rsum[qh];
        s += __shfl_xor(s, 16, 64);
        s += __shfl_xor(s, 32, 64);
        const int q = q0 + qh * 16 + l16;
        if (q < L_MAX) {
            const float inv = 1.f / s;
#pragma unroll
            for (int dh = 0; dh < 2; dh++) {
                ushort4 pk;
                pk.x = f2b(oacc[dh][qh][0] * inv);
                pk.y = f2b(oacc[dh][qh][1] * inv);
                pk.z = f2b(oacc[dh][qh][2] * inv);
                pk.w = f2b(oacc[dh][qh][3] * inv);
                *(ushort4*)(o + ((size_t)(g * L_MAX + q)) * DIM + hh * 32 + dh * 16 + quad * 4) = pk;
            }
        }
    }
}

// y = LN(y + res [+ res2 [+ res3 + res4]]) * g + b; wave-per-row, no LDS/barriers.
__global__ __launch_bounds__(256) void ln_res(
    float* __restrict__ y, const float* __restrict__ res,
    const float* __restrict__ res2, const float* __restrict__ res3,
    const float* __restrict__ res4,
    const float* __restrict__ g, const float* __restrict__ b,
    ushort* __restrict__ yb)
{
    const int r = blockIdx.x * 4 + (threadIdx.x >> 6);
    const int lane = threadIdx.x & 63;
    const size_t base = (size_t)r * DIM + lane * 2;
    float2 v = *(const float2*)(y + base);
    {
        float2 a = *(const float2*)(res + base);
        v.x += a.x; v.y += a.y;
    }
    if (res2) {
        float2 a = *(const float2*)(res2 + base);
        v.x += a.x; v.y += a.y;
    }
    if (res3) {
        float2 a = *(const float2*)(res3 + base);
        float2 c = *(const float2*)(res4 + base);
        v.x += a.x + c.x; v.y += a.y + c.y;
    }
    float s = v.x + v.y;
#pragma unroll
    for (int off = 32; off; off >>= 1) s += __shfl_xor(s, off, 64);
    const float mean = s * (1.f / 128.f);
    const float dx = v.x - mean, dy = v.y - mean;
    float q = dx * dx + dy * dy;
#pragma unroll
    for (int off = 32; off; off >>= 1) q += __shfl_xor(q, off, 64);
    const float rst = rsqrtf(q * (1.f / 128.f) + 1e-5f);
    const float2 gg = *(const float2*)(g + lane * 2);
    const float2 bb = *(const float2*)(b + lane * 2);
    float2 ov;
    ov.x = dx * rst * gg.x + bb.x;
    ov.y = dy * rst * gg.y + bb.y;
    *(float2*)(y + base) = ov;
    ushort2 pk;
    pk.x = f2b(ov.x);
    pk.y = f2b(ov.y);
    *(ushort2*)(yb + base) = pk;
}

// parallel mean-pool: grid (genre, 17 segments of 40 rows)
__global__ __launch_bounds__(256) void pool_partial(
    const float* __restrict__ y, const int* __restrict__ cnt, float* __restrict__ pooled)
{
    __shared__ float sh[128];
    const int g = blockIdx.x, seg = blockIdx.y, t = threadIdx.x;
    const int c = t & 127, h = t >> 7;
    const int L = cnt[g];
    const int k0 = seg * 40, k1 = min(k0 + 40, L);
    float s = 0.f;
    for (int k = k0 + h; k < k1; k += 2) s += y[((size_t)g * L_MAX + k) * DIM + c];
    if (h) sh[c] = s;
    __syncthreads();
    if (!h) {
        float tot = s + sh[c];
        if (k0 < L) atomicAdd(&pooled[g * DIM + c], tot / (float)max(L, 1));
    }
}

__global__ void build_fin(const float* __restrict__ acc, const float* __restrict__ pooled,
                          const int* __restrict__ midx, const int* __restrict__ genre,
                          ushort* __restrict__ A2)
{
    const int i = blockIdx.x, t = threadIdx.x;
    float v = (t < 128) ? acc[(size_t)midx[i] * DIM + t]
                        : pooled[genre[i] * DIM + (t - 128)];
    A2[(size_t)i * 256 + t] = f2b(v);
}

__global__ void scatter_movies(const float* __restrict__ fused, const int* __restrict__ midx,
                               float* __restrict__ out)
{
    const int i = blockIdx.x, c = threadIdx.x;
    out[(size_t)midx[i] * DIM + c] = fused[(size_t)i * DIM + c];
}

extern "C" void kernel_launch(void* const* d_in, const int* in_sizes, int n_in,
                              void* d_out, int out_size, void* d_ws, size_t ws_size,
                              hipStream_t stream)
{
    const float* x      = (const float*)d_in[0];
    const int* e[3]     = { (const int*)d_in[1], (const int*)d_in[2], (const int*)d_in[3] };
    const int* midx     = (const int*)d_in[4];
    const int* genre    = (const int*)d_in[5];
    const float* gatW   = (const float*)d_in[6];
    const float* attS   = (const float*)d_in[7];
    const float* attD   = (const float*)d_in[8];
    const float* gatB   = (const float*)d_in[9];
    const float* decW   = (const float*)d_in[10];
    const float* decB   = (const float*)d_in[11];
    const float* qkvW   = (const float*)d_in[12];
    const float* qkvB   = (const float*)d_in[13];
    const float* outW   = (const float*)d_in[14];
    const float* outB   = (const float*)d_in[15];
    const float* ln1g   = (const float*)d_in[16];
    const float* ln1b   = (const float*)d_in[17];
    const float* ln2g   = (const float*)d_in[18];
    const float* ln2b   = (const float*)d_in[19];
    const float* fw1    = (const float*)d_in[20];
    const float* fb1    = (const float*)d_in[21];
    const float* fw2    = (const float*)d_in[22];
    const float* fb2    = (const float*)d_in[23];
    const float* fusW   = (const float*)d_in[24];
    const float* fusB   = (const float*)d_in[25];
    float* out = (float*)d_out;

    // ---- workspace layout ----
    float* ws  = (float*)d_ws;
    float* acc = out;                             // final node features live in d_out
    float* R   = ws + 6400000;
    // stage A (ws low region + R):
    ushort* xb   = (ushort*)(ws);                 // 6.4M shorts
    ushort* gatWb= (ushort*)(ws + 3200000);       // 49,152 shorts
    ushort* decWb= (ushort*)(ws + 3224576);       // 49,152 shorts
    float*  als3 = ws + 3249152;                  // 600,000
    float*  ald3 = ws + 3849152;                  // 600,000
    int*    off3 = (int*)(ws + 4449152);          // 150,000
    int*    deg3 = (int*)(ws + 4599152);          // 150,000
    ushort* hb3  = (ushort*)(R);                  // 3 x 6.4M shorts
    ushort* gbx3 = (ushort*)(R + 9600000);        // 3 x 6.4M shorts
    int*   bcur  = (int*)(R + 19200000);          // 4,704 (3*98 x 16-int lines)
    int*   ebuf  = (int*)(R + 19204736);          // 1,354,752
    int*   srcs3 = (int*)(R + 20559488);          // 1,505,280 -> ends R+22,064,768
    // stage B (aliases stage A's R region):
    float*  ybuf  = R;                            // 2,611,200
    float*  tmp   = R + 2611200;                  // 2,611,200
    ushort* ybx   = (ushort*)(R + 5222400);       // 2,611,200 shorts
    ushort* attnb = (ushort*)(R + 6528000);       // 2,611,200 shorts
    ushort* qkvb  = (ushort*)(R + 7833600);       // 5,222,400 shorts (Q,K stride 256)
    ushort* vtg   = (ushort*)(R + 10444800);      // 2,611,200 shorts (V^T [128][20400])
    ushort* finb  = (ushort*)(R + 11750400);      // 5,222,400 shorts
    float*  tmp2  = R + 14361600;                 // 2,611,200 (FFN partial q1)
    float*  tmp3  = R + 16972800;                 // 2,611,200 (FFN partial q2)
    float*  tmp4  = R + 19584000;                 // 2,611,200 (FFN partial q3)
    float*  pooled= R + 22195200;                 // 3,840
    int*    cntb  = (int*)(R + 22199040);         // 32
    int*    posb  = cntb + 32;                    // 20,400
    ushort* qkvWb = (ushort*)(R + 22220000);      // 196,608 shorts
    ushort* outWb = (ushort*)(R + 22318304);      // 65,536 shorts
    ushort* fw1b  = (ushort*)(R + 22351072);      // 1,048,576 shorts
    ushort* fw2b  = (ushort*)(R + 22875360);      // 1,048,576 shorts
    ushort* fusWb = (ushort*)(R + 23399648);      // 32,768 shorts

    // ================= weight conversions (one launch) + x =================
    cvt_w<<<dim3(512, 7), 256, 0, stream>>>(
        gatW, decW, qkvW, outW, fw1, fw2, fusW,
        gatWb, decWb, qkvWb, outWb, fw1b, fw2b, fusWb);
    cvt32<<<(6400000 / 8 + 255) / 256, 256, 0, stream>>>(x, xb, 6400000 / 8);

    // ================= bucketed CSR build (all 3 hops) =================
    csr_initb<<<(3 * NBKT + 255) / 256, 256, 0, stream>>>(bcur);
    csr_route<<<dim3((N_EDGES + 4095) / 4096, 3), 256, 0, stream>>>(
        e[0], e[1], e[2], bcur, ebuf);
    csr_build<<<dim3(NBKT, 3), 256, 0, stream>>>(bcur, ebuf, off3, deg3, srcs3);

    // ================= Stage A: 3-hop GAT (hop-merged launches) =================
    hop_gemm<<<dim3(391, 1, 3), 256, 0, stream>>>(
        xb, gatWb, attS, attD, hb3, als3, ald3, N_NODES);
    gat_gather<<<dim3(N_NODES * 64 / 256, 3), 256, 0, stream>>>(
        off3, deg3, srcs3, hb3, als3, ald3, gatB, gbx3);
    dec3_gemm<<<391, 256, 0, stream>>>(gbx3, decWb, decB, acc, N_NODES);

    // ================= Stage B: genre transformer =================
    hipMemsetAsync(cntb, 0, 32 * 4, stream);
    calc_pos<<<(N_MOVIE + 255) / 256, 256, 0, stream>>>(genre, posb, cntb, N_MOVIE);
    build_y<<<N_MOVIE, 128, 0, stream>>>(acc, midx, genre, posb, ybuf, ybx);

    for (int l = 0; l < N_LAYERS; l++) {
        qkv_gemm<<<dim3(160, 3), 256, 0, stream>>>(
            ybx, qkvWb + (size_t)l * 384 * DIM, qkvB + l * 384, qkvb, vtg, NROWS);
        flash_attn<<<dim3(6, 4, 30), 256, 0, stream>>>(qkvb, vtg, cntb, attnb);
        proj_ln<<<(NROWS + 63) / 64, 256, 0, stream>>>(
            attnb, outWb + (size_t)l * DIM * DIM, outB + l * DIM,
            ybuf, ln1g + l * DIM, ln1b + l * DIM, ybx, NROWS);
        ffn_fused<<<dim3((NROWS + 127) / 128, 4), 256, 0, stream>>>(
            ybx, fw1b + (size_t)l * FF * DIM, fb1 + (size_t)l * FF,
            fw2b + (size_t)l * DIM * FF, fb2 + (size_t)l * DIM,
            tmp, tmp2, tmp3, tmp4, NROWS);
        ln_res<<<NROWS / 4, 256, 0, stream>>>(ybuf, tmp, tmp2, tmp3, tmp4,
                                              ln2g + l * DIM, ln2b + l * DIM, ybx);
    }

    hipMemsetAsync(pooled, 0, 3840 * 4, stream);
    pool_partial<<<dim3(N_GENRE, 17), 256, 0, stream>>>(ybuf, cntb, pooled);
    build_fin<<<N_MOVIE, 256, 0, stream>>>(acc, pooled, midx, genre, finb);
    gemm_lds<64, 1, 0, 0><<<dim3(319, 1, 1), 256, 0, stream>>>(
        finb, fusWb, fusB, tmp, NROWS, DIM, 256, 1.f, 0, 0);

    scatter_movies<<<N_MOVIE, 128, 0, stream>>>(tmp, midx, out);
}